// Round 8
// baseline (252.660 us; speedup 1.0000x reference)
//
#include <hip/hip_runtime.h>
#include <hip/hip_bf16.h>
#include <math.h>

#define N 4096
#define G 2048
#define H1 512
#define H2 128
#define HEADS 8
#define EMB 16
#define C 20
#define S 4
#define CH 64
#define CIN_D (H2 + EMB)   // 144
#define KD_PAD 160         // CIN_D padded to multiple of 32
#define CAP 128
#define EPSV 1e-6f

typedef __attribute__((ext_vector_type(8))) short short8;
typedef __attribute__((ext_vector_type(8))) short bf16x8;
typedef __attribute__((ext_vector_type(4))) float f32x4;

__device__ __forceinline__ unsigned short f2b(float x) {
    __hip_bfloat16 h = __float2bfloat16(x);
    return *reinterpret_cast<unsigned short*>(&h);
}
__device__ __forceinline__ float b2f(unsigned short u) {
    unsigned int x = ((unsigned int)u) << 16;
    return __uint_as_float(x);
}
// Stirling lgamma: ~1e-7 rel for x>=8 (shift loop for smaller x; untaken here
// since th = exp(5) ~ 148).
__device__ __forceinline__ float lgamma_fast(float x) {
    float sh = 0.f;
    while (x < 8.f) { sh -= __logf(x); x += 1.f; }
    float ix = 1.f / x;
    float lx = __logf(x);
    return (x - 0.5f) * lx - x + 0.91893853f
         + ix * (0.08333333f - 0.00277778f * ix * ix) + sh;
}

// ---------------- CSR build from dense binary adjacency ----------------
__global__ void build_csr(const float* __restrict__ adj, int* __restrict__ col_idx,
                          int* __restrict__ row_cnt) {
    int i = blockIdx.x;
    int lane = threadIdx.x;  // 64
    int cnt = 0;
    const float4* row4 = (const float4*)(adj + (size_t)i * N);
    int* cols = col_idx + (size_t)i * CAP;
    unsigned long long lmask = (1ull << lane) - 1ull;
    for (int c = 0; c < N / 256; ++c) {
        float4 v = row4[c * 64 + lane];
        float vv[4] = {v.x, v.y, v.z, v.w};
        #pragma unroll
        for (int s = 0; s < 4; ++s) {
            unsigned long long m = __ballot(vv[s] != 0.f);
            if (vv[s] != 0.f) {
                int idx = cnt + __popcll(m & lmask);
                if (idx < CAP) cols[idx] = c * 256 + lane * 4 + s;
            }
            cnt += __popcll(m);
        }
    }
    if (lane == 0) row_cnt[i] = cnt < CAP ? cnt : CAP;
}

// ---------------- fp32 -> bf16 convert (vectorized) ----------------
__global__ void f2bf_vec(const float* __restrict__ in, unsigned short* __restrict__ out, int n4) {
    int i = blockIdx.x * 256 + threadIdx.x;
    if (i >= n4) return;
    float4 v = ((const float4*)in)[i];
    ushort4 o;
    o.x = f2b(v.x); o.y = f2b(v.y); o.z = f2b(v.z); o.w = f2b(v.w);
    ((ushort4*)out)[i] = o;
}

// Wd1 [512][144] -> bf16 padded [512][160]
__global__ void convert_wd1(const float* __restrict__ in, unsigned short* __restrict__ out) {
    int idx = blockIdx.x * 256 + threadIdx.x;
    if (idx >= H1 * KD_PAD) return;
    int n = idx / KD_PAD, k = idx - n * KD_PAD;
    out[idx] = f2b(k < CIN_D ? in[n * CIN_D + k] : 0.f);
}

// ---------------- bf16 MFMA GEMM, optional split-K ----------------
#define LDP 40
template<int FM, int OBF, int KS>
__global__ __launch_bounds__(256) void gemm_mfma(const unsigned short* __restrict__ A,
                                                 const unsigned short* __restrict__ B,
                                                 const float* __restrict__ bias,
                                                 void* __restrict__ Cout,
                                                 int M, int Nc, int K) {
    constexpr int BMT = FM * 32;
    __shared__ short As[BMT * LDP];
    __shared__ short Bs[128 * LDP];
    int bn = blockIdx.x, bm = blockIdx.y;
    int kz = (KS > 1) ? blockIdx.z : 0;
    int t = threadIdx.x;
    int lane = t & 63, wid = t >> 6;
    int wr = wid >> 1, wc = wid & 1;
    f32x4 acc[FM][4] = {};
    const short* Ag = (const short*)A + (size_t)(bm * BMT) * K;
    const short* Bg = (const short*)B + (size_t)(bn * 128) * K;
    int r0 = t >> 2, q0 = t & 3;
    int rbase = (lane & 15);
    int koff = (lane >> 4) * 8;
    int kbeg = kz * (K / KS), kend = kbeg + K / KS;

    for (int k0 = kbeg; k0 < kend; k0 += 32) {
        short8 a0 = *(const short8*)(Ag + (size_t)r0 * K + k0 + q0 * 8);
        short8 a1;
        if constexpr (FM == 4) a1 = *(const short8*)(Ag + (size_t)(r0 + 64) * K + k0 + q0 * 8);
        short8 b0 = *(const short8*)(Bg + (size_t)r0 * K + k0 + q0 * 8);
        short8 b1 = *(const short8*)(Bg + (size_t)(r0 + 64) * K + k0 + q0 * 8);
        __syncthreads();
        *(short8*)(As + r0 * LDP + q0 * 8) = a0;
        if constexpr (FM == 4) *(short8*)(As + (r0 + 64) * LDP + q0 * 8) = a1;
        *(short8*)(Bs + r0 * LDP + q0 * 8) = b0;
        *(short8*)(Bs + (r0 + 64) * LDP + q0 * 8) = b1;
        __syncthreads();
        bf16x8 af[FM], bfr[4];
        #pragma unroll
        for (int m = 0; m < FM; ++m)
            af[m] = *(const bf16x8*)(As + (wr * FM * 16 + m * 16 + rbase) * LDP + koff);
        #pragma unroll
        for (int n = 0; n < 4; ++n)
            bfr[n] = *(const bf16x8*)(Bs + (wc * 64 + n * 16 + rbase) * LDP + koff);
        #pragma unroll
        for (int m = 0; m < FM; ++m)
            #pragma unroll
            for (int n = 0; n < 4; ++n)
                acc[m][n] = __builtin_amdgcn_mfma_f32_16x16x32_bf16(af[m], bfr[n], acc[m][n], 0, 0, 0);
    }
    int colb = bn * 128 + wc * 64;
    int rowb = bm * BMT + wr * FM * 16;
    #pragma unroll
    for (int m = 0; m < FM; ++m) {
        #pragma unroll
        for (int n = 0; n < 4; ++n) {
            int col = colb + n * 16 + (lane & 15);
            int row0 = rowb + m * 16 + (lane >> 4) * 4;
            if constexpr (KS > 1) {
                float* Cp = (float*)Cout + (size_t)kz * M * Nc;
                #pragma unroll
                for (int r = 0; r < 4; ++r)
                    Cp[(size_t)(row0 + r) * Nc + col] = acc[m][n][r];
            } else {
                float bs = bias[col];
                #pragma unroll
                for (int r = 0; r < 4; ++r) {
                    float v = acc[m][n][r] + bs;
                    if constexpr (OBF)
                        ((unsigned short*)Cout)[(size_t)(row0 + r) * Nc + col] = f2b(v);
                    else
                        ((float*)Cout)[(size_t)(row0 + r) * Nc + col] = v;
                }
            }
        }
    }
}

// ---------------- split-K reduce ----------------
template<int KS, int OBF>
__global__ __launch_bounds__(256) void reduce_k(const float* __restrict__ Cp,
                                                const float* __restrict__ bias,
                                                void* __restrict__ out,
                                                int total4, int ncmask) {
    int i = blockIdx.x * 256 + threadIdx.x;
    if (i >= total4) return;
    float4 s = ((const float4*)Cp)[i];
    #pragma unroll
    for (int ks = 1; ks < KS; ++ks) {
        float4 v = ((const float4*)(Cp + (size_t)ks * total4 * 4))[i];
        s.x += v.x; s.y += v.y; s.z += v.z; s.w += v.w;
    }
    int col = (i * 4) & ncmask;
    s.x += bias[col]; s.y += bias[col + 1]; s.z += bias[col + 2]; s.w += bias[col + 3];
    if constexpr (OBF) {
        ushort4 o;
        o.x = f2b(s.x); o.y = f2b(s.y); o.z = f2b(s.z); o.w = f2b(s.w);
        ((ushort4*)out)[i] = o;
    } else {
        ((float4*)out)[i] = s;
    }
}

// ---------------- fused reconstruction GEMM + (nf - Xr)^2 row-reduce (bf16 nf) ----------------
__global__ __launch_bounds__(256) void gemm_recon_sq(const unsigned short* __restrict__ A,
                                                     const unsigned short* __restrict__ B,
                                                     const float* __restrict__ bias,
                                                     const unsigned short* __restrict__ nfb,
                                                     float* __restrict__ sq_part) {
    constexpr int K = H1;
    __shared__ short As[128 * LDP];
    __shared__ short Bs[128 * LDP];
    __shared__ float red[4][64];
    int bn = blockIdx.x, bm = blockIdx.y;
    int t = threadIdx.x;
    int lane = t & 63, wid = t >> 6;
    int wr = wid >> 1, wc = wid & 1;
    f32x4 acc[4][4] = {};
    const short* Ag = (const short*)A + (size_t)(bm * 128) * K;
    const short* Bg = (const short*)B + (size_t)(bn * 128) * K;
    int r0 = t >> 2, q0 = t & 3;
    int rbase = (lane & 15);
    int koff = (lane >> 4) * 8;

    for (int k0 = 0; k0 < K; k0 += 32) {
        short8 a0 = *(const short8*)(Ag + (size_t)r0 * K + k0 + q0 * 8);
        short8 a1 = *(const short8*)(Ag + (size_t)(r0 + 64) * K + k0 + q0 * 8);
        short8 b0 = *(const short8*)(Bg + (size_t)r0 * K + k0 + q0 * 8);
        short8 b1 = *(const short8*)(Bg + (size_t)(r0 + 64) * K + k0 + q0 * 8);
        __syncthreads();
        *(short8*)(As + r0 * LDP + q0 * 8) = a0;
        *(short8*)(As + (r0 + 64) * LDP + q0 * 8) = a1;
        *(short8*)(Bs + r0 * LDP + q0 * 8) = b0;
        *(short8*)(Bs + (r0 + 64) * LDP + q0 * 8) = b1;
        __syncthreads();
        bf16x8 af[4], bfr[4];
        #pragma unroll
        for (int m = 0; m < 4; ++m)
            af[m] = *(const bf16x8*)(As + (wr * 64 + m * 16 + rbase) * LDP + koff);
        #pragma unroll
        for (int n = 0; n < 4; ++n)
            bfr[n] = *(const bf16x8*)(Bs + (wc * 64 + n * 16 + rbase) * LDP + koff);
        #pragma unroll
        for (int m = 0; m < 4; ++m)
            #pragma unroll
            for (int n = 0; n < 4; ++n)
                acc[m][n] = __builtin_amdgcn_mfma_f32_16x16x32_bf16(af[m], bfr[n], acc[m][n], 0, 0, 0);
    }
    int colb = bn * 128 + wc * 64;
    int rowb = bm * 128 + wr * 64;
    float part[4][4];
    #pragma unroll
    for (int m = 0; m < 4; ++m) {
        #pragma unroll
        for (int r = 0; r < 4; ++r) part[m][r] = 0.f;
        #pragma unroll
        for (int n = 0; n < 4; ++n) {
            int col = colb + n * 16 + (lane & 15);
            float bs = bias[col];
            int row0 = rowb + m * 16 + (lane >> 4) * 4;
            #pragma unroll
            for (int r = 0; r < 4; ++r) {
                float d = b2f(nfb[(size_t)(row0 + r) * G + col]) - (acc[m][n][r] + bs);
                part[m][r] += d * d;
            }
        }
    }
    #pragma unroll
    for (int m = 0; m < 4; ++m)
        #pragma unroll
        for (int r = 0; r < 4; ++r) {
            float v = part[m][r];
            v += __shfl_xor(v, 1); v += __shfl_xor(v, 2);
            v += __shfl_xor(v, 4); v += __shfl_xor(v, 8);
            part[m][r] = v;
        }
    if ((lane & 15) == 0) {
        int q = lane >> 4;
        #pragma unroll
        for (int m = 0; m < 4; ++m)
            #pragma unroll
            for (int r = 0; r < 4; ++r)
                red[wid][m * 16 + q * 4 + r] = part[m][r];
    }
    __syncthreads();
    if (t < 128) {
        int wr2 = t >> 6, loc = t & 63;
        float v = red[wr2 * 2 + 0][loc] + red[wr2 * 2 + 1][loc];
        sq_part[(size_t)(bm * 128 + t) * 16 + bn] = v;
    }
}

// ---------------- NB log-likelihood v3 ----------------
// Tile 32 rows x 256 cols; block 256 = 4 waves; wave owns 8 rows; lane owns 4
// consecutive cols. bd computed as 8-row register block: 20 b128 + 160 bcast
// LDS reads per 2048 elements. All global reads coalesced float4 (SoA tables).
#define TCOLS 256
#define TROWS 32
__global__ __launch_bounds__(256) void nb_loss(const float* __restrict__ beta,
                                               const float* __restrict__ basis,
                                               const float* __restrict__ cm,
                                               const int* __restrict__ slab,
                                               const float* __restrict__ muf,
                                               const float* __restrict__ kco,
                                               const float* __restrict__ th_a,
                                               const float* __restrict__ eg_a,
                                               const float* __restrict__ gm_a,
                                               const float* __restrict__ ax_a,
                                               float* __restrict__ ll_part) {
    __shared__ float sbasis[C][TCOLS];     // 20 KB
    __shared__ float sbeta[TROWS][C];      // 2.5 KB
    int bc = blockIdx.x, br = blockIdx.y;
    int t = threadIdx.x;
    int gc0 = bc * TCOLS;
    for (int idx = t; idx < C * TCOLS; idx += 256) {
        int c = idx >> 8, g = idx & 255;
        sbasis[c][g] = basis[c * G + gc0 + g];
    }
    int r0 = br * TROWS;
    for (int idx = t; idx < TROWS * C; idx += 256) {
        int r = idx / C, c = idx - r * C;
        sbeta[r][c] = beta[(size_t)(r0 + r) * C + c];
    }
    __syncthreads();
    int w = t >> 6, lane = t & 63;
    int c0 = lane * 4;
    int rw = w * 8;
    f32x4 bd[8] = {};
    #pragma unroll
    for (int cc = 0; cc < C; ++cc) {
        f32x4 bv = *(const f32x4*)&sbasis[cc][c0];
        #pragma unroll
        for (int r8 = 0; r8 < 8; ++r8)
            bd[r8] += sbeta[rw + r8][cc] * bv;
    }
    int colg = gc0 + c0;
    #pragma unroll
    for (int r8 = 0; r8 < 8; ++r8) {
        int row = r0 + rw + r8;
        int sl = slab[row];
        float mufv = muf[row], kcov = kco[row];
        size_t sg0 = (size_t)sl * G + colg;
        f32x4 th4 = *(const f32x4*)(th_a + sg0);
        f32x4 eg4 = *(const f32x4*)(eg_a + sg0);
        f32x4 gm4 = *(const f32x4*)(gm_a + sg0);
        f32x4 ax4 = *(const f32x4*)(ax_a + sg0);
        f32x4 k4  = *(const f32x4*)(cm + (size_t)row * G + colg);
        float acc = 0.f;
        #pragma unroll
        for (int jj = 0; jj < 4; ++jj) {
            float th = th4[jj], k = k4[jj];
            float ebd = bd[r8][jj] + EPSV;
            float lbd = __logf(ebd);
            float mu = mufv * ebd * eg4[jj];
            float lgx = lgamma_fast(k + th + EPSV);
            acc += lgx + ax4[jj] - (th + k) * __logf(th + mu + EPSV)
                 + k * (kcov + lbd + gm4[jj]);
        }
        #pragma unroll
        for (int m = 32; m; m >>= 1) acc += __shfl_xor(acc, m);
        if (lane == 0) ll_part[(size_t)row * 8 + bc] = acc;
    }
}

// ---------------- per-head attention dot products (bf16 H) ----------------
__global__ void head_dots(const unsigned short* __restrict__ Hb, const float* __restrict__ v0,
                          const float* __restrict__ v1, float* __restrict__ hv0,
                          float* __restrict__ hv1) {
    int i = blockIdx.x;
    int lane = threadIdx.x;  // 64
    #pragma unroll
    for (int h = 0; h < HEADS; ++h) {
        float v = b2f(Hb[(size_t)i * H1 + h * CH + lane]);
        float p0 = v * v0[h * CH + lane];
        float p1 = v * v1[h * CH + lane];
        #pragma unroll
        for (int m = 32; m; m >>= 1) {
            p0 += __shfl_xor(p0, m);
            p1 += __shfl_xor(p1, m);
        }
        if (lane == 0) {
            hv0[i * HEADS + h] = p0;
            hv1[i * HEADS + h] = p1;
        }
    }
}

// ---------------- per-(node,edge,head) normalized attention weights ----------------
__global__ void edge_weights(const float* __restrict__ hv0, const float* __restrict__ hv1,
                             const int* __restrict__ col_idx, const int* __restrict__ row_cnt,
                             float* __restrict__ ew) {
    int i = blockIdx.x;
    int lane = threadIdx.x;  // 64
    int cnt = row_cnt[i];
    const int* cols = col_idx + (size_t)i * CAP;
    int e0 = lane, e1 = lane + 64;
    int j0 = (e0 < cnt) ? cols[e0] : 0;
    int j1 = (e1 < cnt) ? cols[e1] : 0;
    #pragma unroll
    for (int h = 0; h < HEADS; ++h) {
        float a0 = hv0[i * HEADS + h];
        float w0 = 0.f, w1 = 0.f;
        if (e0 < cnt) {
            float x = a0 + hv1[j0 * HEADS + h];
            w0 = __expf(1.f / (1.f + __expf(-x)) - 0.5f);
        }
        if (e1 < cnt) {
            float x = a0 + hv1[j1 * HEADS + h];
            w1 = __expf(1.f / (1.f + __expf(-x)) - 0.5f);
        }
        float den = w0 + w1;
        #pragma unroll
        for (int m = 32; m; m >>= 1) den += __shfl_xor(den, m);
        float inv = 1.f / den;
        if (e0 < cnt) ew[((size_t)i * CAP + e0) * HEADS + h] = w0 * inv;
        if (e1 < cnt) ew[((size_t)i * CAP + e1) * HEADS + h] = w1 * inv;
    }
}

// ---------------- sparse aggregation ----------------
__global__ __launch_bounds__(512) void attn_agg2(const unsigned short* __restrict__ Hb,
                                                 const float* __restrict__ ew,
                                                 const int* __restrict__ col_idx,
                                                 const int* __restrict__ row_cnt,
                                                 unsigned short* __restrict__ out) {
    __shared__ float red[8][64 * 8];   // 16 KB
    int i = blockIdx.x;
    int t = threadIdx.x;
    int slot = t >> 6;
    int cg = t & 63;
    int h = cg >> 3;
    int cnt = row_cnt[i];
    const int* cols = col_idx + (size_t)i * CAP;
    float acc[8];
    #pragma unroll
    for (int k = 0; k < 8; ++k) acc[k] = 0.f;
    for (int e = slot; e < cnt; e += 8) {
        int j = cols[e];
        float wv = ew[((size_t)i * CAP + e) * HEADS + h];
        short8 hv = ((const short8*)(Hb + (size_t)j * H1))[cg];
        #pragma unroll
        for (int k = 0; k < 8; ++k)
            acc[k] += wv * b2f((unsigned short)hv[k]);
    }
    #pragma unroll
    for (int k = 0; k < 8; ++k) red[slot][cg * 8 + k] = acc[k];
    __syncthreads();
    if (slot < 4) {
        #pragma unroll
        for (int k = 0; k < 8; ++k) red[slot][cg * 8 + k] += red[slot + 4][cg * 8 + k];
    }
    __syncthreads();
    if (slot < 2) {
        #pragma unroll
        for (int k = 0; k < 8; ++k) red[slot][cg * 8 + k] += red[slot + 2][cg * 8 + k];
    }
    __syncthreads();
    if (slot == 0) {
        short8 o;
        #pragma unroll
        for (int k = 0; k < 8; ++k) {
            float v = red[0][cg * 8 + k] + red[1][cg * 8 + k];
            v = (v > 0.f) ? v : expm1f(v);
            o[k] = (short)f2b(v);
        }
        ((short8*)(out + (size_t)i * H1))[cg] = o;
    }
}

// ---------------- per-node: beta (fp32), muf/kco, Xd_bf ----------------
__global__ void pernode(const float* __restrict__ Z, const float* __restrict__ emb_table,
                        const int* __restrict__ slab, const float* __restrict__ Wb,
                        const float* __restrict__ bb, const float* __restrict__ Wa,
                        const float* __restrict__ ba, const float* __restrict__ lib,
                        float* __restrict__ beta, float* __restrict__ muf,
                        float* __restrict__ kco, unsigned short* __restrict__ Xdb) {
    int i = blockIdx.x;
    int lane = threadIdx.x;  // 64
    __shared__ float sZ[H2];
    __shared__ float sE[EMB];
    __shared__ float sLog[C];
    __shared__ float sAl;
    sZ[lane] = Z[(size_t)i * H2 + lane];
    sZ[64 + lane] = Z[(size_t)i * H2 + 64 + lane];
    int s = slab[i];
    if (lane < EMB) sE[lane] = emb_table[s * EMB + lane];
    __syncthreads();
    Xdb[(size_t)i * KD_PAD + lane] = f2b(sZ[lane]);
    Xdb[(size_t)i * KD_PAD + 64 + lane] = f2b(sZ[64 + lane]);
    if (lane < EMB) Xdb[(size_t)i * KD_PAD + H2 + lane] = f2b(sE[lane]);
    if (lane < KD_PAD - CIN_D) Xdb[(size_t)i * KD_PAD + CIN_D + lane] = 0;
    if (lane < C) {
        float acc = bb[lane];
        for (int k = 0; k < H2; ++k) {
            float z = sZ[k];
            float e = z > 0.f ? z : expm1f(z);
            acc += e * Wb[lane * H2 + k];
        }
        sLog[lane] = acc;
    }
    __syncthreads();
    if (lane == 0) {
        float mx = sLog[0];
        for (int c = 1; c < C; ++c) mx = fmaxf(mx, sLog[c]);
        float sm = 0.f;
        for (int c = 0; c < C; ++c) { float e = __expf(sLog[c] - mx); sLog[c] = e; sm += e; }
        for (int c = 0; c < C; ++c) sLog[c] /= sm;
    }
    __syncthreads();
    if (lane < C) beta[(size_t)i * C + lane] = sLog[lane];
    float x0 = sZ[lane];        x0 = x0 > 0.f ? x0 : expm1f(x0);
    float x1 = sZ[64 + lane];   x1 = x1 > 0.f ? x1 : expm1f(x1);
    float p = x0 * Wa[lane] + x1 * Wa[64 + lane];
    if (lane < EMB) {
        float x2 = sE[lane];    x2 = x2 > 0.f ? x2 : expm1f(x2);
        p += x2 * Wa[H2 + lane];
    }
    #pragma unroll
    for (int m = 32; m; m >>= 1) p += __shfl_xor(p, m);
    if (lane == 0) sAl = p + ba[0];
    __syncthreads();
    if (lane == 0) {
        float A = sAl, L = lib[i];
        muf[i] = L * __expf(A);
        kco[i] = __logf(L) + A;
    }
}

// ---------------- per-(slice,gene) tables (SoA) ----------------
__global__ void theta_tables(const float* __restrict__ logtheta, const float* __restrict__ gamma,
                             float* __restrict__ th_a, float* __restrict__ eg_a,
                             float* __restrict__ gm_a, float* __restrict__ ax_a) {
    int idx = blockIdx.x * 256 + threadIdx.x;
    if (idx >= S * G) return;
    float th = __expf(logtheta[idx]);
    float gm = gamma[idx];
    th_a[idx] = th;
    eg_a[idx] = __expf(gm);
    gm_a[idx] = gm;
    ax_a[idx] = th * __logf(th + EPSV) - lgammaf(th + EPSV);
}

// ---------------- two-stage final reduce ----------------
__global__ void row_reduce(const float* __restrict__ ll_part, const float* __restrict__ sq_part,
                           float* __restrict__ part_ll, float* __restrict__ part_sq) {
    int blk = blockIdx.x, lane = threadIdx.x;
    int row = blk * 64 + lane;
    float s1 = 0.f, s2 = 0.f;
    #pragma unroll
    for (int j = 0; j < 8; ++j) s1 += ll_part[(size_t)row * 8 + j];
    #pragma unroll
    for (int j = 0; j < 16; ++j) s2 += sq_part[(size_t)row * 16 + j];
    float b = sqrtf(s2);
    #pragma unroll
    for (int m = 32; m; m >>= 1) { s1 += __shfl_xor(s1, m); b += __shfl_xor(b, m); }
    if (lane == 0) { part_ll[blk] = s1; part_sq[blk] = b; }
}

__global__ void finalize2(const float* __restrict__ part_ll, const float* __restrict__ part_sq,
                          float* __restrict__ out) {
    int lane = threadIdx.x;
    float a = part_ll[lane], b = part_sq[lane];
    #pragma unroll
    for (int m = 32; m; m >>= 1) { a += __shfl_xor(a, m); b += __shfl_xor(b, m); }
    if (lane == 0) out[0] = -(a / (float)N) + 0.1f * (b / (float)N);
}

extern "C" void kernel_launch(void* const* d_in, const int* in_sizes, int n_in,
                              void* d_out, int out_size, void* d_ws, size_t ws_size,
                              hipStream_t stream) {
    const float* adj       = (const float*)d_in[0];
    const float* node_f    = (const float*)d_in[1];
    const float* count_m   = (const float*)d_in[2];
    const float* lib       = (const float*)d_in[3];
    const int*   slab      = (const int*)d_in[4];
    const float* basis     = (const float*)d_in[5];
    const float* We1       = (const float*)d_in[6];
    const float* be1       = (const float*)d_in[7];
    const float* v0e1      = (const float*)d_in[8];
    const float* v1e1      = (const float*)d_in[9];
    const float* W2        = (const float*)d_in[10];
    const float* b2        = (const float*)d_in[11];
    const float* Wd1       = (const float*)d_in[12];
    const float* bd1       = (const float*)d_in[13];
    const float* v0d1      = (const float*)d_in[14];
    const float* v1d1      = (const float*)d_in[15];
    const float* Wd2       = (const float*)d_in[16];
    const float* bd2       = (const float*)d_in[17];
    const float* Wa        = (const float*)d_in[18];
    const float* ba        = (const float*)d_in[19];
    const float* Wb        = (const float*)d_in[20];
    const float* bb        = (const float*)d_in[21];
    const float* gamma     = (const float*)d_in[22];
    const float* logtheta  = (const float*)d_in[23];
    const float* emb_table = (const float*)d_in[24];
    float* out = (float*)d_out;

    char* w = (char*)d_ws;
    auto alloc = [&](size_t bytes) { void* p = (void*)w; w += (bytes + 255) & ~(size_t)255; return p; };
    int*   col_idx = (int*)  alloc((size_t)N * CAP * 4);
    int*   row_cnt = (int*)  alloc((size_t)N * 4);
    unsigned short* Hlin_bf = (unsigned short*)alloc((size_t)N * H1 * 2);
    unsigned short* Hgat_bf = (unsigned short*)alloc((size_t)N * H1 * 2);
    float* Z       = (float*)alloc((size_t)N * H2 * 4);
    unsigned short* Xd_bf   = (unsigned short*)alloc((size_t)N * KD_PAD * 2);
    float* beta    = (float*)alloc((size_t)N * C * 4);
    float* muf     = (float*)alloc((size_t)N * 4);
    float* kco     = (float*)alloc((size_t)N * 4);
    float* hv0     = (float*)alloc((size_t)N * HEADS * 4);
    float* hv1     = (float*)alloc((size_t)N * HEADS * 4);
    float* ew      = (float*)alloc((size_t)N * CAP * HEADS * 4);   // 16 MB
    float* th_a    = (float*)alloc((size_t)S * G * 4);
    float* eg_a    = (float*)alloc((size_t)S * G * 4);
    float* gm_a    = (float*)alloc((size_t)S * G * 4);
    float* ax_a    = (float*)alloc((size_t)S * G * 4);
    float* Cp      = (float*)alloc((size_t)4 * N * H1 * 4);        // 32 MB split-K partials
    float* ll_part = (float*)alloc((size_t)N * 8 * 4);
    float* sq_part = (float*)alloc((size_t)N * 16 * 4);
    float* part_ll = (float*)alloc(64 * 4);
    float* part_sq = (float*)alloc(64 * 4);
    unsigned short* nf_bf    = (unsigned short*)alloc((size_t)N * G * 2);
    unsigned short* We1_bf   = (unsigned short*)alloc((size_t)H1 * G * 2);
    unsigned short* W2_bf    = (unsigned short*)alloc((size_t)H2 * H1 * 2);
    unsigned short* Wd1_bf   = (unsigned short*)alloc((size_t)H1 * KD_PAD * 2);
    unsigned short* Wd2_bf   = (unsigned short*)alloc((size_t)G * H1 * 2);

    // tables + conversions
    build_csr<<<dim3(N), dim3(64), 0, stream>>>(adj, col_idx, row_cnt);
    theta_tables<<<dim3((S * G + 255) / 256), dim3(256), 0, stream>>>(
        logtheta, gamma, th_a, eg_a, gm_a, ax_a);
    f2bf_vec<<<dim3((N * G / 4 + 255) / 256), dim3(256), 0, stream>>>(node_f, nf_bf, N * G / 4);
    f2bf_vec<<<dim3((H1 * G / 4 + 255) / 256), dim3(256), 0, stream>>>(We1, We1_bf, H1 * G / 4);
    f2bf_vec<<<dim3((H2 * H1 / 4 + 255) / 256), dim3(256), 0, stream>>>(W2, W2_bf, H2 * H1 / 4);
    convert_wd1<<<dim3((H1 * KD_PAD + 255) / 256), dim3(256), 0, stream>>>(Wd1, Wd1_bf);
    f2bf_vec<<<dim3((G * H1 / 4 + 255) / 256), dim3(256), 0, stream>>>(Wd2, Wd2_bf, G * H1 / 4);

    // 1. encoder linear, split-K=4 -> reduce -> bf16 Hlin
    gemm_mfma<2, 0, 4><<<dim3(H1 / 128, N / 64, 4), dim3(256), 0, stream>>>(
        nf_bf, We1_bf, be1, Cp, N, H1, G);
    reduce_k<4, 1><<<dim3((N * H1 / 4 + 255) / 256), dim3(256), 0, stream>>>(
        Cp, be1, Hlin_bf, N * H1 / 4, H1 - 1);
    // 2-3. encoder attention
    head_dots<<<dim3(N), dim3(64), 0, stream>>>(Hlin_bf, v0e1, v1e1, hv0, hv1);
    edge_weights<<<dim3(N), dim3(64), 0, stream>>>(hv0, hv1, col_idx, row_cnt, ew);
    attn_agg2<<<dim3(N), dim3(512), 0, stream>>>(Hlin_bf, ew, col_idx, row_cnt, Hgat_bf);
    // 4. Z, split-K=8 -> reduce -> fp32 Z
    gemm_mfma<2, 0, 8><<<dim3(H2 / 128, N / 64, 8), dim3(256), 0, stream>>>(
        Hgat_bf, W2_bf, b2, Cp, N, H2, H1);
    reduce_k<8, 0><<<dim3((N * H2 / 4 + 255) / 256), dim3(256), 0, stream>>>(
        Cp, b2, Z, N * H2 / 4, H2 - 1);
    // 5. per-node
    pernode<<<dim3(N), dim3(64), 0, stream>>>(Z, emb_table, slab, Wb, bb, Wa, ba, lib,
                                              beta, muf, kco, Xd_bf);
    // 5b. NB log-likelihood v3
    nb_loss<<<dim3(G / TCOLS, N / TROWS), dim3(256), 0, stream>>>(
        beta, basis, count_m, slab, muf, kco, th_a, eg_a, gm_a, ax_a, ll_part);
    // 6. decoder linear -> bf16
    gemm_mfma<2, 1, 1><<<dim3(H1 / 128, N / 64), dim3(256), 0, stream>>>(
        Xd_bf, Wd1_bf, bd1, Hlin_bf, N, H1, KD_PAD);
    // 7-8. decoder attention
    head_dots<<<dim3(N), dim3(64), 0, stream>>>(Hlin_bf, v0d1, v1d1, hv0, hv1);
    edge_weights<<<dim3(N), dim3(64), 0, stream>>>(hv0, hv1, col_idx, row_cnt, ew);
    attn_agg2<<<dim3(N), dim3(512), 0, stream>>>(Hlin_bf, ew, col_idx, row_cnt, Hgat_bf);
    // 9. fused reconstruction GEMM + sq-norm (bf16 nf)
    gemm_recon_sq<<<dim3(G / 128, N / 128), dim3(256), 0, stream>>>(
        Hgat_bf, Wd2_bf, bd2, nf_bf, sq_part);
    // 10-11. reduce
    row_reduce<<<dim3(64), dim3(64), 0, stream>>>(ll_part, sq_part, part_ll, part_sq);
    finalize2<<<dim3(1), dim3(64), 0, stream>>>(part_ll, part_sq, out);
}

// Round 9
// 221.295 us; speedup vs baseline: 1.1417x; 1.1417x over previous
//
#include <hip/hip_runtime.h>
#include <hip/hip_bf16.h>
#include <math.h>

#define N 4096
#define G 2048
#define H1 512
#define H2 128
#define HEADS 8
#define EMB 16
#define C 20
#define S 4
#define CH 64
#define CIN_D (H2 + EMB)   // 144
#define KD_PAD 160         // CIN_D padded to multiple of 32
#define KB_PAD 32          // C padded to 32
#define CAP 128
#define EPSV 1e-6f

typedef __attribute__((ext_vector_type(8))) short short8;
typedef __attribute__((ext_vector_type(8))) short bf16x8;
typedef __attribute__((ext_vector_type(4))) float f32x4;

__device__ __forceinline__ unsigned short f2b(float x) {
    __hip_bfloat16 h = __float2bfloat16(x);
    return *reinterpret_cast<unsigned short*>(&h);
}
__device__ __forceinline__ float b2f(unsigned short u) {
    unsigned int x = ((unsigned int)u) << 16;
    return __uint_as_float(x);
}
// Stirling lgamma: ~1e-7 rel for x>=8 (shift loop for smaller x; untaken here
// since th = exp(5) ~ 148).
__device__ __forceinline__ float lgamma_fast(float x) {
    float sh = 0.f;
    while (x < 8.f) { sh -= __logf(x); x += 1.f; }
    float ix = 1.f / x;
    float lx = __logf(x);
    return (x - 0.5f) * lx - x + 0.91893853f
         + ix * (0.08333333f - 0.00277778f * ix * ix) + sh;
}

// ---------------- CSR build from dense binary adjacency ----------------
__global__ void build_csr(const float* __restrict__ adj, int* __restrict__ col_idx,
                          int* __restrict__ row_cnt) {
    int i = blockIdx.x;
    int lane = threadIdx.x;  // 64
    int cnt = 0;
    const float4* row4 = (const float4*)(adj + (size_t)i * N);
    int* cols = col_idx + (size_t)i * CAP;
    unsigned long long lmask = (1ull << lane) - 1ull;
    for (int c = 0; c < N / 256; ++c) {
        float4 v = row4[c * 64 + lane];
        float vv[4] = {v.x, v.y, v.z, v.w};
        #pragma unroll
        for (int s = 0; s < 4; ++s) {
            unsigned long long m = __ballot(vv[s] != 0.f);
            if (vv[s] != 0.f) {
                int idx = cnt + __popcll(m & lmask);
                if (idx < CAP) cols[idx] = c * 256 + lane * 4 + s;
            }
            cnt += __popcll(m);
        }
    }
    if (lane == 0) row_cnt[i] = cnt < CAP ? cnt : CAP;
}

// ---------------- fp32 -> bf16 convert (vectorized) ----------------
__global__ void f2bf_vec(const float* __restrict__ in, unsigned short* __restrict__ out, int n4) {
    int i = blockIdx.x * 256 + threadIdx.x;
    if (i >= n4) return;
    float4 v = ((const float4*)in)[i];
    ushort4 o;
    o.x = f2b(v.x); o.y = f2b(v.y); o.z = f2b(v.z); o.w = f2b(v.w);
    ((ushort4*)out)[i] = o;
}

// Wd1 [512][144] -> bf16 padded [512][160]
__global__ void convert_wd1(const float* __restrict__ in, unsigned short* __restrict__ out) {
    int idx = blockIdx.x * 256 + threadIdx.x;
    if (idx >= H1 * KD_PAD) return;
    int n = idx / KD_PAD, k = idx - n * KD_PAD;
    out[idx] = f2b(k < CIN_D ? in[n * CIN_D + k] : 0.f);
}

// basis [20][2048] -> basisT bf16 [2048][32] (K-padded)
__global__ void convert_basisT(const float* __restrict__ basis, unsigned short* __restrict__ out) {
    int idx = blockIdx.x * 256 + threadIdx.x;
    if (idx >= G * KB_PAD) return;
    int g = idx >> 5, c = idx & 31;
    out[idx] = f2b(c < C ? basis[c * G + g] : 0.f);
}

// ---------------- bf16 MFMA GEMM, optional split-K; bias may be null ----------------
#define LDP 40
template<int FM, int OBF, int KS>
__global__ __launch_bounds__(256) void gemm_mfma(const unsigned short* __restrict__ A,
                                                 const unsigned short* __restrict__ B,
                                                 const float* __restrict__ bias,
                                                 void* __restrict__ Cout,
                                                 int M, int Nc, int K) {
    constexpr int BMT = FM * 32;
    __shared__ short As[BMT * LDP];
    __shared__ short Bs[128 * LDP];
    int bn = blockIdx.x, bm = blockIdx.y;
    int kz = (KS > 1) ? blockIdx.z : 0;
    int t = threadIdx.x;
    int lane = t & 63, wid = t >> 6;
    int wr = wid >> 1, wc = wid & 1;
    f32x4 acc[FM][4] = {};
    const short* Ag = (const short*)A + (size_t)(bm * BMT) * K;
    const short* Bg = (const short*)B + (size_t)(bn * 128) * K;
    int r0 = t >> 2, q0 = t & 3;
    int rbase = (lane & 15);
    int koff = (lane >> 4) * 8;
    int kbeg = kz * (K / KS), kend = kbeg + K / KS;

    for (int k0 = kbeg; k0 < kend; k0 += 32) {
        short8 a0 = *(const short8*)(Ag + (size_t)r0 * K + k0 + q0 * 8);
        short8 a1;
        if constexpr (FM == 4) a1 = *(const short8*)(Ag + (size_t)(r0 + 64) * K + k0 + q0 * 8);
        short8 b0 = *(const short8*)(Bg + (size_t)r0 * K + k0 + q0 * 8);
        short8 b1 = *(const short8*)(Bg + (size_t)(r0 + 64) * K + k0 + q0 * 8);
        __syncthreads();
        *(short8*)(As + r0 * LDP + q0 * 8) = a0;
        if constexpr (FM == 4) *(short8*)(As + (r0 + 64) * LDP + q0 * 8) = a1;
        *(short8*)(Bs + r0 * LDP + q0 * 8) = b0;
        *(short8*)(Bs + (r0 + 64) * LDP + q0 * 8) = b1;
        __syncthreads();
        bf16x8 af[FM], bfr[4];
        #pragma unroll
        for (int m = 0; m < FM; ++m)
            af[m] = *(const bf16x8*)(As + (wr * FM * 16 + m * 16 + rbase) * LDP + koff);
        #pragma unroll
        for (int n = 0; n < 4; ++n)
            bfr[n] = *(const bf16x8*)(Bs + (wc * 64 + n * 16 + rbase) * LDP + koff);
        #pragma unroll
        for (int m = 0; m < FM; ++m)
            #pragma unroll
            for (int n = 0; n < 4; ++n)
                acc[m][n] = __builtin_amdgcn_mfma_f32_16x16x32_bf16(af[m], bfr[n], acc[m][n], 0, 0, 0);
    }
    int colb = bn * 128 + wc * 64;
    int rowb = bm * BMT + wr * FM * 16;
    #pragma unroll
    for (int m = 0; m < FM; ++m) {
        #pragma unroll
        for (int n = 0; n < 4; ++n) {
            int col = colb + n * 16 + (lane & 15);
            int row0 = rowb + m * 16 + (lane >> 4) * 4;
            if constexpr (KS > 1) {
                float* Cp = (float*)Cout + (size_t)kz * M * Nc;
                #pragma unroll
                for (int r = 0; r < 4; ++r)
                    Cp[(size_t)(row0 + r) * Nc + col] = acc[m][n][r];
            } else {
                float bs = bias ? bias[col] : 0.f;
                #pragma unroll
                for (int r = 0; r < 4; ++r) {
                    float v = acc[m][n][r] + bs;
                    if constexpr (OBF)
                        ((unsigned short*)Cout)[(size_t)(row0 + r) * Nc + col] = f2b(v);
                    else
                        ((float*)Cout)[(size_t)(row0 + r) * Nc + col] = v;
                }
            }
        }
    }
}

// ---------------- split-K reduce ----------------
template<int KS, int OBF>
__global__ __launch_bounds__(256) void reduce_k(const float* __restrict__ Cp,
                                                const float* __restrict__ bias,
                                                void* __restrict__ out,
                                                int total4, int ncmask) {
    int i = blockIdx.x * 256 + threadIdx.x;
    if (i >= total4) return;
    float4 s = ((const float4*)Cp)[i];
    #pragma unroll
    for (int ks = 1; ks < KS; ++ks) {
        float4 v = ((const float4*)(Cp + (size_t)ks * total4 * 4))[i];
        s.x += v.x; s.y += v.y; s.z += v.z; s.w += v.w;
    }
    int col = (i * 4) & ncmask;
    s.x += bias[col]; s.y += bias[col + 1]; s.z += bias[col + 2]; s.w += bias[col + 3];
    if constexpr (OBF) {
        ushort4 o;
        o.x = f2b(s.x); o.y = f2b(s.y); o.z = f2b(s.z); o.w = f2b(s.w);
        ((ushort4*)out)[i] = o;
    } else {
        ((float4*)out)[i] = s;
    }
}

// ---------------- fused reconstruction GEMM + (nf - Xr)^2 row-reduce (bf16 nf) ----------------
__global__ __launch_bounds__(256) void gemm_recon_sq(const unsigned short* __restrict__ A,
                                                     const unsigned short* __restrict__ B,
                                                     const float* __restrict__ bias,
                                                     const unsigned short* __restrict__ nfb,
                                                     float* __restrict__ sq_part) {
    constexpr int K = H1;
    __shared__ short As[128 * LDP];
    __shared__ short Bs[128 * LDP];
    __shared__ float red[4][64];
    int bn = blockIdx.x, bm = blockIdx.y;
    int t = threadIdx.x;
    int lane = t & 63, wid = t >> 6;
    int wr = wid >> 1, wc = wid & 1;
    f32x4 acc[4][4] = {};
    const short* Ag = (const short*)A + (size_t)(bm * 128) * K;
    const short* Bg = (const short*)B + (size_t)(bn * 128) * K;
    int r0 = t >> 2, q0 = t & 3;
    int rbase = (lane & 15);
    int koff = (lane >> 4) * 8;

    for (int k0 = 0; k0 < K; k0 += 32) {
        short8 a0 = *(const short8*)(Ag + (size_t)r0 * K + k0 + q0 * 8);
        short8 a1 = *(const short8*)(Ag + (size_t)(r0 + 64) * K + k0 + q0 * 8);
        short8 b0 = *(const short8*)(Bg + (size_t)r0 * K + k0 + q0 * 8);
        short8 b1 = *(const short8*)(Bg + (size_t)(r0 + 64) * K + k0 + q0 * 8);
        __syncthreads();
        *(short8*)(As + r0 * LDP + q0 * 8) = a0;
        *(short8*)(As + (r0 + 64) * LDP + q0 * 8) = a1;
        *(short8*)(Bs + r0 * LDP + q0 * 8) = b0;
        *(short8*)(Bs + (r0 + 64) * LDP + q0 * 8) = b1;
        __syncthreads();
        bf16x8 af[4], bfr[4];
        #pragma unroll
        for (int m = 0; m < 4; ++m)
            af[m] = *(const bf16x8*)(As + (wr * 64 + m * 16 + rbase) * LDP + koff);
        #pragma unroll
        for (int n = 0; n < 4; ++n)
            bfr[n] = *(const bf16x8*)(Bs + (wc * 64 + n * 16 + rbase) * LDP + koff);
        #pragma unroll
        for (int m = 0; m < 4; ++m)
            #pragma unroll
            for (int n = 0; n < 4; ++n)
                acc[m][n] = __builtin_amdgcn_mfma_f32_16x16x32_bf16(af[m], bfr[n], acc[m][n], 0, 0, 0);
    }
    int colb = bn * 128 + wc * 64;
    int rowb = bm * 128 + wr * 64;
    float part[4][4];
    #pragma unroll
    for (int m = 0; m < 4; ++m) {
        #pragma unroll
        for (int r = 0; r < 4; ++r) part[m][r] = 0.f;
        #pragma unroll
        for (int n = 0; n < 4; ++n) {
            int col = colb + n * 16 + (lane & 15);
            float bs = bias[col];
            int row0 = rowb + m * 16 + (lane >> 4) * 4;
            #pragma unroll
            for (int r = 0; r < 4; ++r) {
                float d = b2f(nfb[(size_t)(row0 + r) * G + col]) - (acc[m][n][r] + bs);
                part[m][r] += d * d;
            }
        }
    }
    #pragma unroll
    for (int m = 0; m < 4; ++m)
        #pragma unroll
        for (int r = 0; r < 4; ++r) {
            float v = part[m][r];
            v += __shfl_xor(v, 1); v += __shfl_xor(v, 2);
            v += __shfl_xor(v, 4); v += __shfl_xor(v, 8);
            part[m][r] = v;
        }
    if ((lane & 15) == 0) {
        int q = lane >> 4;
        #pragma unroll
        for (int m = 0; m < 4; ++m)
            #pragma unroll
            for (int r = 0; r < 4; ++r)
                red[wid][m * 16 + q * 4 + r] = part[m][r];
    }
    __syncthreads();
    if (t < 128) {
        int wr2 = t >> 6, loc = t & 63;
        float v = red[wr2 * 2 + 0][loc] + red[wr2 * 2 + 1][loc];
        sq_part[(size_t)(bm * 128 + t) * 16 + bn] = v;
    }
}

// ---------------- NB log-likelihood v4: pure elementwise, wave-per-row ----------------
// BD precomputed by MFMA GEMM. 6 coalesced b128 streams; no LDS; low VGPR.
__global__ __launch_bounds__(256) void nb_loss_ew(const float* __restrict__ BD,
                                                  const float* __restrict__ cm,
                                                  const int* __restrict__ slab,
                                                  const float* __restrict__ muf,
                                                  const float* __restrict__ kco,
                                                  const float* __restrict__ th_a,
                                                  const float* __restrict__ eg_a,
                                                  const float* __restrict__ gm_a,
                                                  const float* __restrict__ ax_a,
                                                  float* __restrict__ ll_row) {
    int row = blockIdx.x * 4 + (threadIdx.x >> 6);
    int lane = threadIdx.x & 63;
    int sl = slab[row];
    float mufv = muf[row], kcov = kco[row];
    const float* bdr = BD + (size_t)row * G;
    const float* cmr = cm + (size_t)row * G;
    size_t sgb = (size_t)sl * G;
    float acc = 0.f;
    #pragma unroll 2
    for (int it = 0; it < G / 256; ++it) {
        int c = it * 256 + lane * 4;
        f32x4 bd4 = *(const f32x4*)(bdr + c);
        f32x4 k4  = *(const f32x4*)(cmr + c);
        f32x4 th4 = *(const f32x4*)(th_a + sgb + c);
        f32x4 eg4 = *(const f32x4*)(eg_a + sgb + c);
        f32x4 gm4 = *(const f32x4*)(gm_a + sgb + c);
        f32x4 ax4 = *(const f32x4*)(ax_a + sgb + c);
        #pragma unroll
        for (int j = 0; j < 4; ++j) {
            float th = th4[j], k = k4[j];
            float ebd = bd4[j] + EPSV;
            float lbd = __logf(ebd);
            float mu = mufv * ebd * eg4[j];
            float lgx = lgamma_fast(k + th + EPSV);
            acc += lgx + ax4[j] - (th + k) * __logf(th + mu + EPSV)
                 + k * (kcov + lbd + gm4[j]);
        }
    }
    #pragma unroll
    for (int m = 32; m; m >>= 1) acc += __shfl_xor(acc, m);
    if (lane == 0) ll_row[row] = acc;
}

// ---------------- per-head attention dot products (bf16 H) ----------------
__global__ void head_dots(const unsigned short* __restrict__ Hb, const float* __restrict__ v0,
                          const float* __restrict__ v1, float* __restrict__ hv0,
                          float* __restrict__ hv1) {
    int i = blockIdx.x;
    int lane = threadIdx.x;  // 64
    #pragma unroll
    for (int h = 0; h < HEADS; ++h) {
        float v = b2f(Hb[(size_t)i * H1 + h * CH + lane]);
        float p0 = v * v0[h * CH + lane];
        float p1 = v * v1[h * CH + lane];
        #pragma unroll
        for (int m = 32; m; m >>= 1) {
            p0 += __shfl_xor(p0, m);
            p1 += __shfl_xor(p1, m);
        }
        if (lane == 0) {
            hv0[i * HEADS + h] = p0;
            hv1[i * HEADS + h] = p1;
        }
    }
}

// ---------------- per-(node,edge,head) normalized attention weights ----------------
__global__ void edge_weights(const float* __restrict__ hv0, const float* __restrict__ hv1,
                             const int* __restrict__ col_idx, const int* __restrict__ row_cnt,
                             float* __restrict__ ew) {
    int i = blockIdx.x;
    int lane = threadIdx.x;  // 64
    int cnt = row_cnt[i];
    const int* cols = col_idx + (size_t)i * CAP;
    int e0 = lane, e1 = lane + 64;
    int j0 = (e0 < cnt) ? cols[e0] : 0;
    int j1 = (e1 < cnt) ? cols[e1] : 0;
    #pragma unroll
    for (int h = 0; h < HEADS; ++h) {
        float a0 = hv0[i * HEADS + h];
        float w0 = 0.f, w1 = 0.f;
        if (e0 < cnt) {
            float x = a0 + hv1[j0 * HEADS + h];
            w0 = __expf(1.f / (1.f + __expf(-x)) - 0.5f);
        }
        if (e1 < cnt) {
            float x = a0 + hv1[j1 * HEADS + h];
            w1 = __expf(1.f / (1.f + __expf(-x)) - 0.5f);
        }
        float den = w0 + w1;
        #pragma unroll
        for (int m = 32; m; m >>= 1) den += __shfl_xor(den, m);
        float inv = 1.f / den;
        if (e0 < cnt) ew[((size_t)i * CAP + e0) * HEADS + h] = w0 * inv;
        if (e1 < cnt) ew[((size_t)i * CAP + e1) * HEADS + h] = w1 * inv;
    }
}

// ---------------- sparse aggregation ----------------
__global__ __launch_bounds__(512) void attn_agg2(const unsigned short* __restrict__ Hb,
                                                 const float* __restrict__ ew,
                                                 const int* __restrict__ col_idx,
                                                 const int* __restrict__ row_cnt,
                                                 unsigned short* __restrict__ out) {
    __shared__ float red[8][64 * 8];   // 16 KB
    int i = blockIdx.x;
    int t = threadIdx.x;
    int slot = t >> 6;
    int cg = t & 63;
    int h = cg >> 3;
    int cnt = row_cnt[i];
    const int* cols = col_idx + (size_t)i * CAP;
    float acc[8];
    #pragma unroll
    for (int k = 0; k < 8; ++k) acc[k] = 0.f;
    for (int e = slot; e < cnt; e += 8) {
        int j = cols[e];
        float wv = ew[((size_t)i * CAP + e) * HEADS + h];
        short8 hv = ((const short8*)(Hb + (size_t)j * H1))[cg];
        #pragma unroll
        for (int k = 0; k < 8; ++k)
            acc[k] += wv * b2f((unsigned short)hv[k]);
    }
    #pragma unroll
    for (int k = 0; k < 8; ++k) red[slot][cg * 8 + k] = acc[k];
    __syncthreads();
    if (slot < 4) {
        #pragma unroll
        for (int k = 0; k < 8; ++k) red[slot][cg * 8 + k] += red[slot + 4][cg * 8 + k];
    }
    __syncthreads();
    if (slot < 2) {
        #pragma unroll
        for (int k = 0; k < 8; ++k) red[slot][cg * 8 + k] += red[slot + 2][cg * 8 + k];
    }
    __syncthreads();
    if (slot == 0) {
        short8 o;
        #pragma unroll
        for (int k = 0; k < 8; ++k) {
            float v = red[0][cg * 8 + k] + red[1][cg * 8 + k];
            v = (v > 0.f) ? v : expm1f(v);
            o[k] = (short)f2b(v);
        }
        ((short8*)(out + (size_t)i * H1))[cg] = o;
    }
}

// ---------------- per-node: beta_bf (padded), muf/kco, Xd_bf ----------------
__global__ void pernode(const float* __restrict__ Z, const float* __restrict__ emb_table,
                        const int* __restrict__ slab, const float* __restrict__ Wb,
                        const float* __restrict__ bb, const float* __restrict__ Wa,
                        const float* __restrict__ ba, const float* __restrict__ lib,
                        unsigned short* __restrict__ beta_bf, float* __restrict__ muf,
                        float* __restrict__ kco, unsigned short* __restrict__ Xdb) {
    int i = blockIdx.x;
    int lane = threadIdx.x;  // 64
    __shared__ float sZ[H2];
    __shared__ float sE[EMB];
    __shared__ float sLog[C];
    __shared__ float sAl;
    sZ[lane] = Z[(size_t)i * H2 + lane];
    sZ[64 + lane] = Z[(size_t)i * H2 + 64 + lane];
    int s = slab[i];
    if (lane < EMB) sE[lane] = emb_table[s * EMB + lane];
    __syncthreads();
    Xdb[(size_t)i * KD_PAD + lane] = f2b(sZ[lane]);
    Xdb[(size_t)i * KD_PAD + 64 + lane] = f2b(sZ[64 + lane]);
    if (lane < EMB) Xdb[(size_t)i * KD_PAD + H2 + lane] = f2b(sE[lane]);
    if (lane < KD_PAD - CIN_D) Xdb[(size_t)i * KD_PAD + CIN_D + lane] = 0;
    if (lane < C) {
        float acc = bb[lane];
        for (int k = 0; k < H2; ++k) {
            float z = sZ[k];
            float e = z > 0.f ? z : expm1f(z);
            acc += e * Wb[lane * H2 + k];
        }
        sLog[lane] = acc;
    }
    __syncthreads();
    if (lane == 0) {
        float mx = sLog[0];
        for (int c = 1; c < C; ++c) mx = fmaxf(mx, sLog[c]);
        float sm = 0.f;
        for (int c = 0; c < C; ++c) { float e = __expf(sLog[c] - mx); sLog[c] = e; sm += e; }
        for (int c = 0; c < C; ++c) sLog[c] /= sm;
    }
    __syncthreads();
    if (lane < KB_PAD) beta_bf[(size_t)i * KB_PAD + lane] = (lane < C) ? f2b(sLog[lane]) : 0;
    float x0 = sZ[lane];        x0 = x0 > 0.f ? x0 : expm1f(x0);
    float x1 = sZ[64 + lane];   x1 = x1 > 0.f ? x1 : expm1f(x1);
    float p = x0 * Wa[lane] + x1 * Wa[64 + lane];
    if (lane < EMB) {
        float x2 = sE[lane];    x2 = x2 > 0.f ? x2 : expm1f(x2);
        p += x2 * Wa[H2 + lane];
    }
    #pragma unroll
    for (int m = 32; m; m >>= 1) p += __shfl_xor(p, m);
    if (lane == 0) sAl = p + ba[0];
    __syncthreads();
    if (lane == 0) {
        float A = sAl, L = lib[i];
        muf[i] = L * __expf(A);
        kco[i] = __logf(L) + A;
    }
}

// ---------------- per-(slice,gene) tables (SoA) ----------------
__global__ void theta_tables(const float* __restrict__ logtheta, const float* __restrict__ gamma,
                             float* __restrict__ th_a, float* __restrict__ eg_a,
                             float* __restrict__ gm_a, float* __restrict__ ax_a) {
    int idx = blockIdx.x * 256 + threadIdx.x;
    if (idx >= S * G) return;
    float th = __expf(logtheta[idx]);
    float gm = gamma[idx];
    th_a[idx] = th;
    eg_a[idx] = __expf(gm);
    gm_a[idx] = gm;
    ax_a[idx] = th * __logf(th + EPSV) - lgammaf(th + EPSV);
}

// ---------------- two-stage final reduce ----------------
__global__ void row_reduce(const float* __restrict__ ll_row, const float* __restrict__ sq_part,
                           float* __restrict__ part_ll, float* __restrict__ part_sq) {
    int blk = blockIdx.x, lane = threadIdx.x;
    int row = blk * 64 + lane;
    float s1 = ll_row[row];
    float s2 = 0.f;
    #pragma unroll
    for (int j = 0; j < 16; ++j) s2 += sq_part[(size_t)row * 16 + j];
    float b = sqrtf(s2);
    #pragma unroll
    for (int m = 32; m; m >>= 1) { s1 += __shfl_xor(s1, m); b += __shfl_xor(b, m); }
    if (lane == 0) { part_ll[blk] = s1; part_sq[blk] = b; }
}

__global__ void finalize2(const float* __restrict__ part_ll, const float* __restrict__ part_sq,
                          float* __restrict__ out) {
    int lane = threadIdx.x;
    float a = part_ll[lane], b = part_sq[lane];
    #pragma unroll
    for (int m = 32; m; m >>= 1) { a += __shfl_xor(a, m); b += __shfl_xor(b, m); }
    if (lane == 0) out[0] = -(a / (float)N) + 0.1f * (b / (float)N);
}

extern "C" void kernel_launch(void* const* d_in, const int* in_sizes, int n_in,
                              void* d_out, int out_size, void* d_ws, size_t ws_size,
                              hipStream_t stream) {
    const float* adj       = (const float*)d_in[0];
    const float* node_f    = (const float*)d_in[1];
    const float* count_m   = (const float*)d_in[2];
    const float* lib       = (const float*)d_in[3];
    const int*   slab      = (const int*)d_in[4];
    const float* basis     = (const float*)d_in[5];
    const float* We1       = (const float*)d_in[6];
    const float* be1       = (const float*)d_in[7];
    const float* v0e1      = (const float*)d_in[8];
    const float* v1e1      = (const float*)d_in[9];
    const float* W2        = (const float*)d_in[10];
    const float* b2        = (const float*)d_in[11];
    const float* Wd1       = (const float*)d_in[12];
    const float* bd1       = (const float*)d_in[13];
    const float* v0d1      = (const float*)d_in[14];
    const float* v1d1      = (const float*)d_in[15];
    const float* Wd2       = (const float*)d_in[16];
    const float* bd2       = (const float*)d_in[17];
    const float* Wa        = (const float*)d_in[18];
    const float* ba        = (const float*)d_in[19];
    const float* Wb        = (const float*)d_in[20];
    const float* bb        = (const float*)d_in[21];
    const float* gamma     = (const float*)d_in[22];
    const float* logtheta  = (const float*)d_in[23];
    const float* emb_table = (const float*)d_in[24];
    float* out = (float*)d_out;

    char* w = (char*)d_ws;
    auto alloc = [&](size_t bytes) { void* p = (void*)w; w += (bytes + 255) & ~(size_t)255; return p; };
    int*   col_idx = (int*)  alloc((size_t)N * CAP * 4);
    int*   row_cnt = (int*)  alloc((size_t)N * 4);
    unsigned short* Hlin_bf = (unsigned short*)alloc((size_t)N * H1 * 2);
    unsigned short* Hgat_bf = (unsigned short*)alloc((size_t)N * H1 * 2);
    float* Z       = (float*)alloc((size_t)N * H2 * 4);
    unsigned short* Xd_bf   = (unsigned short*)alloc((size_t)N * KD_PAD * 2);
    unsigned short* beta_bf = (unsigned short*)alloc((size_t)N * KB_PAD * 2);
    float* muf     = (float*)alloc((size_t)N * 4);
    float* kco     = (float*)alloc((size_t)N * 4);
    float* hv0     = (float*)alloc((size_t)N * HEADS * 4);
    float* hv1     = (float*)alloc((size_t)N * HEADS * 4);
    float* ew      = (float*)alloc((size_t)N * CAP * HEADS * 4);   // 16 MB
    float* th_a    = (float*)alloc((size_t)S * G * 4);
    float* eg_a    = (float*)alloc((size_t)S * G * 4);
    float* gm_a    = (float*)alloc((size_t)S * G * 4);
    float* ax_a    = (float*)alloc((size_t)S * G * 4);
    float* Cp      = (float*)alloc((size_t)4 * N * H1 * 4);        // 32 MB split-K partials
    float* BD      = (float*)alloc((size_t)N * G * 4);             // 32 MB beta@basis
    float* ll_row  = (float*)alloc((size_t)N * 4);
    float* sq_part = (float*)alloc((size_t)N * 16 * 4);
    float* part_ll = (float*)alloc(64 * 4);
    float* part_sq = (float*)alloc(64 * 4);
    unsigned short* nf_bf    = (unsigned short*)alloc((size_t)N * G * 2);
    unsigned short* We1_bf   = (unsigned short*)alloc((size_t)H1 * G * 2);
    unsigned short* W2_bf    = (unsigned short*)alloc((size_t)H2 * H1 * 2);
    unsigned short* Wd1_bf   = (unsigned short*)alloc((size_t)H1 * KD_PAD * 2);
    unsigned short* Wd2_bf   = (unsigned short*)alloc((size_t)G * H1 * 2);
    unsigned short* basisT_bf= (unsigned short*)alloc((size_t)G * KB_PAD * 2);

    // tables + conversions
    build_csr<<<dim3(N), dim3(64), 0, stream>>>(adj, col_idx, row_cnt);
    theta_tables<<<dim3((S * G + 255) / 256), dim3(256), 0, stream>>>(
        logtheta, gamma, th_a, eg_a, gm_a, ax_a);
    f2bf_vec<<<dim3((N * G / 4 + 255) / 256), dim3(256), 0, stream>>>(node_f, nf_bf, N * G / 4);
    f2bf_vec<<<dim3((H1 * G / 4 + 255) / 256), dim3(256), 0, stream>>>(We1, We1_bf, H1 * G / 4);
    f2bf_vec<<<dim3((H2 * H1 / 4 + 255) / 256), dim3(256), 0, stream>>>(W2, W2_bf, H2 * H1 / 4);
    convert_wd1<<<dim3((H1 * KD_PAD + 255) / 256), dim3(256), 0, stream>>>(Wd1, Wd1_bf);
    f2bf_vec<<<dim3((G * H1 / 4 + 255) / 256), dim3(256), 0, stream>>>(Wd2, Wd2_bf, G * H1 / 4);
    convert_basisT<<<dim3((G * KB_PAD + 255) / 256), dim3(256), 0, stream>>>(basis, basisT_bf);

    // 1. encoder linear, split-K=4 -> reduce -> bf16 Hlin
    gemm_mfma<2, 0, 4><<<dim3(H1 / 128, N / 64, 4), dim3(256), 0, stream>>>(
        nf_bf, We1_bf, be1, Cp, N, H1, G);
    reduce_k<4, 1><<<dim3((N * H1 / 4 + 255) / 256), dim3(256), 0, stream>>>(
        Cp, be1, Hlin_bf, N * H1 / 4, H1 - 1);
    // 2-3. encoder attention
    head_dots<<<dim3(N), dim3(64), 0, stream>>>(Hlin_bf, v0e1, v1e1, hv0, hv1);
    edge_weights<<<dim3(N), dim3(64), 0, stream>>>(hv0, hv1, col_idx, row_cnt, ew);
    attn_agg2<<<dim3(N), dim3(512), 0, stream>>>(Hlin_bf, ew, col_idx, row_cnt, Hgat_bf);
    // 4. Z, split-K=8 -> reduce -> fp32 Z
    gemm_mfma<2, 0, 8><<<dim3(H2 / 128, N / 64, 8), dim3(256), 0, stream>>>(
        Hgat_bf, W2_bf, b2, Cp, N, H2, H1);
    reduce_k<8, 0><<<dim3((N * H2 / 4 + 255) / 256), dim3(256), 0, stream>>>(
        Cp, b2, Z, N * H2 / 4, H2 - 1);
    // 5. per-node
    pernode<<<dim3(N), dim3(64), 0, stream>>>(Z, emb_table, slab, Wb, bb, Wa, ba, lib,
                                              beta_bf, muf, kco, Xd_bf);
    // 5b. BD = beta @ basis (MFMA, K=32, no bias) -> fp32
    gemm_mfma<2, 0, 1><<<dim3(G / 128, N / 64), dim3(256), 0, stream>>>(
        beta_bf, basisT_bf, nullptr, BD, N, G, KB_PAD);
    // 5c. NB log-likelihood elementwise
    nb_loss_ew<<<dim3(N / 4), dim3(256), 0, stream>>>(
        BD, count_m, slab, muf, kco, th_a, eg_a, gm_a, ax_a, ll_row);
    // 6. decoder linear -> bf16
    gemm_mfma<2, 1, 1><<<dim3(H1 / 128, N / 64), dim3(256), 0, stream>>>(
        Xd_bf, Wd1_bf, bd1, Hlin_bf, N, H1, KD_PAD);
    // 7-8. decoder attention
    head_dots<<<dim3(N), dim3(64), 0, stream>>>(Hlin_bf, v0d1, v1d1, hv0, hv1);
    edge_weights<<<dim3(N), dim3(64), 0, stream>>>(hv0, hv1, col_idx, row_cnt, ew);
    attn_agg2<<<dim3(N), dim3(512), 0, stream>>>(Hlin_bf, ew, col_idx, row_cnt, Hgat_bf);
    // 9. fused reconstruction GEMM + sq-norm (bf16 nf)
    gemm_recon_sq<<<dim3(G / 128, N / 128), dim3(256), 0, stream>>>(
        Hgat_bf, Wd2_bf, bd2, nf_bf, sq_part);
    // 10-11. reduce
    row_reduce<<<dim3(64), dim3(64), 0, stream>>>(ll_row, sq_part, part_ll, part_sq);
    finalize2<<<dim3(1), dim3(64), 0, stream>>>(part_ll, part_sq, out);
}

// Round 10
// 201.701 us; speedup vs baseline: 1.2526x; 1.0971x over previous
//
#include <hip/hip_runtime.h>
#include <hip/hip_bf16.h>
#include <math.h>

#define N 4096
#define G 2048
#define H1 512
#define H2 128
#define HEADS 8
#define EMB 16
#define C 20
#define S 4
#define CH 64
#define CIN_D (H2 + EMB)   // 144
#define KD_PAD 160         // CIN_D padded to multiple of 32
#define KB_PAD 32          // C padded to 32
#define CAP 128
#define EPSV 1e-6f

typedef __attribute__((ext_vector_type(8))) short short8;
typedef __attribute__((ext_vector_type(8))) short bf16x8;
typedef __attribute__((ext_vector_type(4))) float f32x4;

__device__ __forceinline__ unsigned short f2b(float x) {
    __hip_bfloat16 h = __float2bfloat16(x);
    return *reinterpret_cast<unsigned short*>(&h);
}
__device__ __forceinline__ float b2f(unsigned short u) {
    unsigned int x = ((unsigned int)u) << 16;
    return __uint_as_float(x);
}
// Stirling lgamma: ~1e-7 rel for x>=8 (shift loop for smaller x; untaken here
// since th = exp(5) ~ 148).
__device__ __forceinline__ float lgamma_fast(float x) {
    float sh = 0.f;
    while (x < 8.f) { sh -= __logf(x); x += 1.f; }
    float ix = 1.f / x;
    float lx = __logf(x);
    return (x - 0.5f) * lx - x + 0.91893853f
         + ix * (0.08333333f - 0.00277778f * ix * ix) + sh;
}

// ---------------- CSR build from dense binary adjacency ----------------
__global__ void build_csr(const float* __restrict__ adj, int* __restrict__ col_idx,
                          int* __restrict__ row_cnt) {
    int i = blockIdx.x;
    int lane = threadIdx.x;  // 64
    int cnt = 0;
    const float4* row4 = (const float4*)(adj + (size_t)i * N);
    int* cols = col_idx + (size_t)i * CAP;
    unsigned long long lmask = (1ull << lane) - 1ull;
    for (int c = 0; c < N / 256; ++c) {
        float4 v = row4[c * 64 + lane];
        float vv[4] = {v.x, v.y, v.z, v.w};
        #pragma unroll
        for (int s = 0; s < 4; ++s) {
            unsigned long long m = __ballot(vv[s] != 0.f);
            if (vv[s] != 0.f) {
                int idx = cnt + __popcll(m & lmask);
                if (idx < CAP) cols[idx] = c * 256 + lane * 4 + s;
            }
            cnt += __popcll(m);
        }
    }
    if (lane == 0) row_cnt[i] = cnt < CAP ? cnt : CAP;
}

// ---------------- consolidated prep: theta tables + all bf16 conversions ----------------
#define SEG_SG   (S * G)                 // 8192
#define SEG_NF4  (N * G / 4)             // 2097152
#define SEG_WE4  (H1 * G / 4)            // 262144
#define SEG_W24  (H2 * H1 / 4)           // 16384
#define SEG_WD1E (H1 * KD_PAD)           // 81920
#define SEG_WD24 (G * H1 / 4)            // 262144
#define SEG_BTE  (G * KB_PAD)            // 65536
#define PREP_TOTAL (SEG_SG + SEG_NF4 + SEG_WE4 + SEG_W24 + SEG_WD1E + SEG_WD24 + SEG_BTE)

__device__ __forceinline__ void cvt4(const float* __restrict__ in,
                                     unsigned short* __restrict__ out, int i) {
    float4 v = ((const float4*)in)[i];
    ushort4 o;
    o.x = f2b(v.x); o.y = f2b(v.y); o.z = f2b(v.z); o.w = f2b(v.w);
    ((ushort4*)out)[i] = o;
}

__global__ __launch_bounds__(256) void prep(const float* __restrict__ logtheta,
                                            const float* __restrict__ gamma,
                                            float* __restrict__ th_a, float* __restrict__ eg_a,
                                            float* __restrict__ gm_a, float* __restrict__ ax_a,
                                            const float* __restrict__ node_f,
                                            unsigned short* __restrict__ nf_bf,
                                            const float* __restrict__ We1,
                                            unsigned short* __restrict__ We1_bf,
                                            const float* __restrict__ W2,
                                            unsigned short* __restrict__ W2_bf,
                                            const float* __restrict__ Wd1,
                                            unsigned short* __restrict__ Wd1_bf,
                                            const float* __restrict__ Wd2,
                                            unsigned short* __restrict__ Wd2_bf,
                                            const float* __restrict__ basis,
                                            unsigned short* __restrict__ basisT_bf) {
    int idx = blockIdx.x * 256 + threadIdx.x;
    if (idx < SEG_SG) {
        float th = __expf(logtheta[idx]);
        float gm = gamma[idx];
        th_a[idx] = th;
        eg_a[idx] = __expf(gm);
        gm_a[idx] = gm;
        ax_a[idx] = th * __logf(th + EPSV) - lgammaf(th + EPSV);
        return;
    }
    idx -= SEG_SG;
    if (idx < SEG_NF4) { cvt4(node_f, nf_bf, idx); return; }
    idx -= SEG_NF4;
    if (idx < SEG_WE4) { cvt4(We1, We1_bf, idx); return; }
    idx -= SEG_WE4;
    if (idx < SEG_W24) { cvt4(W2, W2_bf, idx); return; }
    idx -= SEG_W24;
    if (idx < SEG_WD1E) {
        int n = idx / KD_PAD, k = idx - n * KD_PAD;
        Wd1_bf[idx] = f2b(k < CIN_D ? Wd1[n * CIN_D + k] : 0.f);
        return;
    }
    idx -= SEG_WD1E;
    if (idx < SEG_WD24) { cvt4(Wd2, Wd2_bf, idx); return; }
    idx -= SEG_WD24;
    if (idx < SEG_BTE) {
        int g = idx >> 5, c = idx & 31;
        basisT_bf[idx] = f2b(c < C ? basis[c * G + g] : 0.f);
    }
}

// ---------------- bf16 MFMA GEMM, optional split-K; bias may be null ----------------
#define LDP 40
template<int FM, int OBF, int KS>
__global__ __launch_bounds__(256) void gemm_mfma(const unsigned short* __restrict__ A,
                                                 const unsigned short* __restrict__ B,
                                                 const float* __restrict__ bias,
                                                 void* __restrict__ Cout,
                                                 int M, int Nc, int K) {
    constexpr int BMT = FM * 32;
    __shared__ short As[BMT * LDP];
    __shared__ short Bs[128 * LDP];
    int bn = blockIdx.x, bm = blockIdx.y;
    int kz = (KS > 1) ? blockIdx.z : 0;
    int t = threadIdx.x;
    int lane = t & 63, wid = t >> 6;
    int wr = wid >> 1, wc = wid & 1;
    f32x4 acc[FM][4] = {};
    const short* Ag = (const short*)A + (size_t)(bm * BMT) * K;
    const short* Bg = (const short*)B + (size_t)(bn * 128) * K;
    int r0 = t >> 2, q0 = t & 3;
    int rbase = (lane & 15);
    int koff = (lane >> 4) * 8;
    int kbeg = kz * (K / KS), kend = kbeg + K / KS;

    for (int k0 = kbeg; k0 < kend; k0 += 32) {
        short8 a0 = *(const short8*)(Ag + (size_t)r0 * K + k0 + q0 * 8);
        short8 a1;
        if constexpr (FM == 4) a1 = *(const short8*)(Ag + (size_t)(r0 + 64) * K + k0 + q0 * 8);
        short8 b0 = *(const short8*)(Bg + (size_t)r0 * K + k0 + q0 * 8);
        short8 b1 = *(const short8*)(Bg + (size_t)(r0 + 64) * K + k0 + q0 * 8);
        __syncthreads();
        *(short8*)(As + r0 * LDP + q0 * 8) = a0;
        if constexpr (FM == 4) *(short8*)(As + (r0 + 64) * LDP + q0 * 8) = a1;
        *(short8*)(Bs + r0 * LDP + q0 * 8) = b0;
        *(short8*)(Bs + (r0 + 64) * LDP + q0 * 8) = b1;
        __syncthreads();
        bf16x8 af[FM], bfr[4];
        #pragma unroll
        for (int m = 0; m < FM; ++m)
            af[m] = *(const bf16x8*)(As + (wr * FM * 16 + m * 16 + rbase) * LDP + koff);
        #pragma unroll
        for (int n = 0; n < 4; ++n)
            bfr[n] = *(const bf16x8*)(Bs + (wc * 64 + n * 16 + rbase) * LDP + koff);
        #pragma unroll
        for (int m = 0; m < FM; ++m)
            #pragma unroll
            for (int n = 0; n < 4; ++n)
                acc[m][n] = __builtin_amdgcn_mfma_f32_16x16x32_bf16(af[m], bfr[n], acc[m][n], 0, 0, 0);
    }
    int colb = bn * 128 + wc * 64;
    int rowb = bm * BMT + wr * FM * 16;
    #pragma unroll
    for (int m = 0; m < FM; ++m) {
        #pragma unroll
        for (int n = 0; n < 4; ++n) {
            int col = colb + n * 16 + (lane & 15);
            int row0 = rowb + m * 16 + (lane >> 4) * 4;
            if constexpr (KS > 1) {
                float* Cp = (float*)Cout + (size_t)kz * M * Nc;
                #pragma unroll
                for (int r = 0; r < 4; ++r)
                    Cp[(size_t)(row0 + r) * Nc + col] = acc[m][n][r];
            } else {
                float bs = bias ? bias[col] : 0.f;
                #pragma unroll
                for (int r = 0; r < 4; ++r) {
                    float v = acc[m][n][r] + bs;
                    if constexpr (OBF)
                        ((unsigned short*)Cout)[(size_t)(row0 + r) * Nc + col] = f2b(v);
                    else
                        ((float*)Cout)[(size_t)(row0 + r) * Nc + col] = v;
                }
            }
        }
    }
}

// ---------------- split-K reduce ----------------
template<int KS, int OBF>
__global__ __launch_bounds__(256) void reduce_k(const float* __restrict__ Cp,
                                                const float* __restrict__ bias,
                                                void* __restrict__ out,
                                                int total4, int ncmask) {
    int i = blockIdx.x * 256 + threadIdx.x;
    if (i >= total4) return;
    float4 s = ((const float4*)Cp)[i];
    #pragma unroll
    for (int ks = 1; ks < KS; ++ks) {
        float4 v = ((const float4*)(Cp + (size_t)ks * total4 * 4))[i];
        s.x += v.x; s.y += v.y; s.z += v.z; s.w += v.w;
    }
    int col = (i * 4) & ncmask;
    s.x += bias[col]; s.y += bias[col + 1]; s.z += bias[col + 2]; s.w += bias[col + 3];
    if constexpr (OBF) {
        ushort4 o;
        o.x = f2b(s.x); o.y = f2b(s.y); o.z = f2b(s.z); o.w = f2b(s.w);
        ((ushort4*)out)[i] = o;
    } else {
        ((float4*)out)[i] = s;
    }
}

// ---------------- fused reconstruction GEMM (64x128 tile) + (nf - Xr)^2 ----------------
__global__ __launch_bounds__(256) void gemm_recon_sq(const unsigned short* __restrict__ A,
                                                     const unsigned short* __restrict__ B,
                                                     const float* __restrict__ bias,
                                                     const unsigned short* __restrict__ nfb,
                                                     float* __restrict__ sq_part) {
    constexpr int K = H1;
    __shared__ short As[64 * LDP];
    __shared__ short Bs[128 * LDP];
    __shared__ float red[4][32];
    int bn = blockIdx.x, bm = blockIdx.y;
    int t = threadIdx.x;
    int lane = t & 63, wid = t >> 6;
    int wr = wid >> 1, wc = wid & 1;
    f32x4 acc[2][4] = {};
    const short* Ag = (const short*)A + (size_t)(bm * 64) * K;
    const short* Bg = (const short*)B + (size_t)(bn * 128) * K;
    int r0 = t >> 2, q0 = t & 3;
    int rbase = (lane & 15);
    int koff = (lane >> 4) * 8;

    for (int k0 = 0; k0 < K; k0 += 32) {
        short8 a0 = *(const short8*)(Ag + (size_t)r0 * K + k0 + q0 * 8);
        short8 b0 = *(const short8*)(Bg + (size_t)r0 * K + k0 + q0 * 8);
        short8 b1 = *(const short8*)(Bg + (size_t)(r0 + 64) * K + k0 + q0 * 8);
        __syncthreads();
        *(short8*)(As + r0 * LDP + q0 * 8) = a0;
        *(short8*)(Bs + r0 * LDP + q0 * 8) = b0;
        *(short8*)(Bs + (r0 + 64) * LDP + q0 * 8) = b1;
        __syncthreads();
        bf16x8 af[2], bfr[4];
        #pragma unroll
        for (int m = 0; m < 2; ++m)
            af[m] = *(const bf16x8*)(As + (wr * 32 + m * 16 + rbase) * LDP + koff);
        #pragma unroll
        for (int n = 0; n < 4; ++n)
            bfr[n] = *(const bf16x8*)(Bs + (wc * 64 + n * 16 + rbase) * LDP + koff);
        #pragma unroll
        for (int m = 0; m < 2; ++m)
            #pragma unroll
            for (int n = 0; n < 4; ++n)
                acc[m][n] = __builtin_amdgcn_mfma_f32_16x16x32_bf16(af[m], bfr[n], acc[m][n], 0, 0, 0);
    }
    int colb = bn * 128 + wc * 64;
    int rowb = bm * 64 + wr * 32;
    float part[2][4];
    #pragma unroll
    for (int m = 0; m < 2; ++m) {
        #pragma unroll
        for (int r = 0; r < 4; ++r) part[m][r] = 0.f;
        #pragma unroll
        for (int n = 0; n < 4; ++n) {
            int col = colb + n * 16 + (lane & 15);
            float bs = bias[col];
            int row0 = rowb + m * 16 + (lane >> 4) * 4;
            #pragma unroll
            for (int r = 0; r < 4; ++r) {
                float d = b2f(nfb[(size_t)(row0 + r) * G + col]) - (acc[m][n][r] + bs);
                part[m][r] += d * d;
            }
        }
    }
    #pragma unroll
    for (int m = 0; m < 2; ++m)
        #pragma unroll
        for (int r = 0; r < 4; ++r) {
            float v = part[m][r];
            v += __shfl_xor(v, 1); v += __shfl_xor(v, 2);
            v += __shfl_xor(v, 4); v += __shfl_xor(v, 8);
            part[m][r] = v;
        }
    if ((lane & 15) == 0) {
        int q = lane >> 4;
        #pragma unroll
        for (int m = 0; m < 2; ++m)
            #pragma unroll
            for (int r = 0; r < 4; ++r)
                red[wid][m * 16 + q * 4 + r] = part[m][r];
    }
    __syncthreads();
    if (t < 64) {
        int wr2 = t >> 5, loc = t & 31;
        float v = red[wr2 * 2 + 0][loc] + red[wr2 * 2 + 1][loc];
        sq_part[(size_t)(bm * 64 + t) * 16 + bn] = v;
    }
}

// ---------------- NB log-likelihood: elementwise, wave-per-row, bf16 BD ----------------
__global__ __launch_bounds__(256) void nb_loss_ew(const unsigned short* __restrict__ BDb,
                                                  const float* __restrict__ cm,
                                                  const int* __restrict__ slab,
                                                  const float* __restrict__ muf,
                                                  const float* __restrict__ kco,
                                                  const float* __restrict__ th_a,
                                                  const float* __restrict__ eg_a,
                                                  const float* __restrict__ gm_a,
                                                  const float* __restrict__ ax_a,
                                                  float* __restrict__ ll_row) {
    int row = blockIdx.x * 4 + (threadIdx.x >> 6);
    int lane = threadIdx.x & 63;
    int sl = slab[row];
    float mufv = muf[row], kcov = kco[row];
    const unsigned short* bdr = BDb + (size_t)row * G;
    const float* cmr = cm + (size_t)row * G;
    size_t sgb = (size_t)sl * G;
    float acc = 0.f;
    #pragma unroll 2
    for (int it = 0; it < G / 256; ++it) {
        int c = it * 256 + lane * 4;
        ushort4 bdu = *(const ushort4*)(bdr + c);
        f32x4 k4  = *(const f32x4*)(cmr + c);
        f32x4 th4 = *(const f32x4*)(th_a + sgb + c);
        f32x4 eg4 = *(const f32x4*)(eg_a + sgb + c);
        f32x4 gm4 = *(const f32x4*)(gm_a + sgb + c);
        f32x4 ax4 = *(const f32x4*)(ax_a + sgb + c);
        float bdv[4] = {b2f(bdu.x), b2f(bdu.y), b2f(bdu.z), b2f(bdu.w)};
        #pragma unroll
        for (int j = 0; j < 4; ++j) {
            float th = th4[j], k = k4[j];
            float ebd = bdv[j] + EPSV;
            float lbd = __logf(ebd);
            float mu = mufv * ebd * eg4[j];
            float lgx = lgamma_fast(k + th + EPSV);
            acc += lgx + ax4[j] - (th + k) * __logf(th + mu + EPSV)
                 + k * (kcov + lbd + gm4[j]);
        }
    }
    #pragma unroll
    for (int m = 32; m; m >>= 1) acc += __shfl_xor(acc, m);
    if (lane == 0) ll_row[row] = acc;
}

// ---------------- per-head attention dot products (bf16 H) ----------------
__global__ void head_dots(const unsigned short* __restrict__ Hb, const float* __restrict__ v0,
                          const float* __restrict__ v1, float* __restrict__ hv0,
                          float* __restrict__ hv1) {
    int i = blockIdx.x;
    int lane = threadIdx.x;  // 64
    #pragma unroll
    for (int h = 0; h < HEADS; ++h) {
        float v = b2f(Hb[(size_t)i * H1 + h * CH + lane]);
        float p0 = v * v0[h * CH + lane];
        float p1 = v * v1[h * CH + lane];
        #pragma unroll
        for (int m = 32; m; m >>= 1) {
            p0 += __shfl_xor(p0, m);
            p1 += __shfl_xor(p1, m);
        }
        if (lane == 0) {
            hv0[i * HEADS + h] = p0;
            hv1[i * HEADS + h] = p1;
        }
    }
}

// ---------------- fused attention: weights in LDS + aggregation + elu -> bf16 ----------------
__global__ __launch_bounds__(512) void attn_fused(const unsigned short* __restrict__ Hb,
                                                  const float* __restrict__ hv0,
                                                  const float* __restrict__ hv1,
                                                  const int* __restrict__ col_idx,
                                                  const int* __restrict__ row_cnt,
                                                  unsigned short* __restrict__ out) {
    __shared__ int scols[CAP];
    __shared__ float sw[CAP][HEADS];     // 4 KB
    __shared__ float sden[HEADS];
    __shared__ float red[8][64 * 8];     // 16 KB
    int i = blockIdx.x;
    int t = threadIdx.x;
    int cnt = row_cnt[i];
    const int* cols = col_idx + (size_t)i * CAP;
    if (t < cnt) scols[t] = cols[t];
    __syncthreads();
    for (int idx = t; idx < cnt * HEADS; idx += 512) {
        int e = idx >> 3, h = idx & 7;
        int j = scols[e];
        float x = hv0[i * HEADS + h] + hv1[j * HEADS + h];
        sw[e][h] = __expf(1.f / (1.f + __expf(-x)) - 0.5f);
    }
    __syncthreads();
    if (t < HEADS) {
        float d = 0.f;
        for (int e = 0; e < cnt; ++e) d += sw[e][t];
        sden[t] = 1.f / d;     // den > 0 (self-loop)
    }
    __syncthreads();
    int slot = t >> 6;
    int cg = t & 63;
    int h = cg >> 3;
    float inv = sden[h];
    float acc[8];
    #pragma unroll
    for (int k = 0; k < 8; ++k) acc[k] = 0.f;
    for (int e = slot; e < cnt; e += 8) {
        int j = scols[e];
        float wv = sw[e][h] * inv;
        short8 hv = ((const short8*)(Hb + (size_t)j * H1))[cg];
        #pragma unroll
        for (int k = 0; k < 8; ++k)
            acc[k] += wv * b2f((unsigned short)hv[k]);
    }
    #pragma unroll
    for (int k = 0; k < 8; ++k) red[slot][cg * 8 + k] = acc[k];
    __syncthreads();
    if (slot < 4) {
        #pragma unroll
        for (int k = 0; k < 8; ++k) red[slot][cg * 8 + k] += red[slot + 4][cg * 8 + k];
    }
    __syncthreads();
    if (slot < 2) {
        #pragma unroll
        for (int k = 0; k < 8; ++k) red[slot][cg * 8 + k] += red[slot + 2][cg * 8 + k];
    }
    __syncthreads();
    if (slot == 0) {
        short8 o;
        #pragma unroll
        for (int k = 0; k < 8; ++k) {
            float v = red[0][cg * 8 + k] + red[1][cg * 8 + k];
            v = (v > 0.f) ? v : expm1f(v);
            o[k] = (short)f2b(v);
        }
        ((short8*)(out + (size_t)i * H1))[cg] = o;
    }
}

// ---------------- per-node: beta_bf (padded), muf/kco, Xd_bf ----------------
__global__ void pernode(const float* __restrict__ Z, const float* __restrict__ emb_table,
                        const int* __restrict__ slab, const float* __restrict__ Wb,
                        const float* __restrict__ bb, const float* __restrict__ Wa,
                        const float* __restrict__ ba, const float* __restrict__ lib,
                        unsigned short* __restrict__ beta_bf, float* __restrict__ muf,
                        float* __restrict__ kco, unsigned short* __restrict__ Xdb) {
    int i = blockIdx.x;
    int lane = threadIdx.x;  // 64
    __shared__ float sZ[H2];
    __shared__ float sE[EMB];
    __shared__ float sLog[C];
    __shared__ float sAl;
    sZ[lane] = Z[(size_t)i * H2 + lane];
    sZ[64 + lane] = Z[(size_t)i * H2 + 64 + lane];
    int s = slab[i];
    if (lane < EMB) sE[lane] = emb_table[s * EMB + lane];
    __syncthreads();
    Xdb[(size_t)i * KD_PAD + lane] = f2b(sZ[lane]);
    Xdb[(size_t)i * KD_PAD + 64 + lane] = f2b(sZ[64 + lane]);
    if (lane < EMB) Xdb[(size_t)i * KD_PAD + H2 + lane] = f2b(sE[lane]);
    if (lane < KD_PAD - CIN_D) Xdb[(size_t)i * KD_PAD + CIN_D + lane] = 0;
    if (lane < C) {
        float acc = bb[lane];
        for (int k = 0; k < H2; ++k) {
            float z = sZ[k];
            float e = z > 0.f ? z : expm1f(z);
            acc += e * Wb[lane * H2 + k];
        }
        sLog[lane] = acc;
    }
    __syncthreads();
    if (lane == 0) {
        float mx = sLog[0];
        for (int c = 1; c < C; ++c) mx = fmaxf(mx, sLog[c]);
        float sm = 0.f;
        for (int c = 0; c < C; ++c) { float e = __expf(sLog[c] - mx); sLog[c] = e; sm += e; }
        for (int c = 0; c < C; ++c) sLog[c] /= sm;
    }
    __syncthreads();
    if (lane < KB_PAD) beta_bf[(size_t)i * KB_PAD + lane] = (lane < C) ? f2b(sLog[lane]) : 0;
    float x0 = sZ[lane];        x0 = x0 > 0.f ? x0 : expm1f(x0);
    float x1 = sZ[64 + lane];   x1 = x1 > 0.f ? x1 : expm1f(x1);
    float p = x0 * Wa[lane] + x1 * Wa[64 + lane];
    if (lane < EMB) {
        float x2 = sE[lane];    x2 = x2 > 0.f ? x2 : expm1f(x2);
        p += x2 * Wa[H2 + lane];
    }
    #pragma unroll
    for (int m = 32; m; m >>= 1) p += __shfl_xor(p, m);
    if (lane == 0) sAl = p + ba[0];
    __syncthreads();
    if (lane == 0) {
        float A = sAl, L = lib[i];
        muf[i] = L * __expf(A);
        kco[i] = __logf(L) + A;
    }
}

// ---------------- two-stage final reduce ----------------
__global__ void row_reduce(const float* __restrict__ ll_row, const float* __restrict__ sq_part,
                           float* __restrict__ part_ll, float* __restrict__ part_sq) {
    int blk = blockIdx.x, lane = threadIdx.x;
    int row = blk * 64 + lane;
    float s1 = ll_row[row];
    float s2 = 0.f;
    #pragma unroll
    for (int j = 0; j < 16; ++j) s2 += sq_part[(size_t)row * 16 + j];
    float b = sqrtf(s2);
    #pragma unroll
    for (int m = 32; m; m >>= 1) { s1 += __shfl_xor(s1, m); b += __shfl_xor(b, m); }
    if (lane == 0) { part_ll[blk] = s1; part_sq[blk] = b; }
}

__global__ void finalize2(const float* __restrict__ part_ll, const float* __restrict__ part_sq,
                          float* __restrict__ out) {
    int lane = threadIdx.x;
    float a = part_ll[lane], b = part_sq[lane];
    #pragma unroll
    for (int m = 32; m; m >>= 1) { a += __shfl_xor(a, m); b += __shfl_xor(b, m); }
    if (lane == 0) out[0] = -(a / (float)N) + 0.1f * (b / (float)N);
}

extern "C" void kernel_launch(void* const* d_in, const int* in_sizes, int n_in,
                              void* d_out, int out_size, void* d_ws, size_t ws_size,
                              hipStream_t stream) {
    const float* adj       = (const float*)d_in[0];
    const float* node_f    = (const float*)d_in[1];
    const float* count_m   = (const float*)d_in[2];
    const float* lib       = (const float*)d_in[3];
    const int*   slab      = (const int*)d_in[4];
    const float* basis     = (const float*)d_in[5];
    const float* We1       = (const float*)d_in[6];
    const float* be1       = (const float*)d_in[7];
    const float* v0e1      = (const float*)d_in[8];
    const float* v1e1      = (const float*)d_in[9];
    const float* W2        = (const float*)d_in[10];
    const float* b2        = (const float*)d_in[11];
    const float* Wd1       = (const float*)d_in[12];
    const float* bd1       = (const float*)d_in[13];
    const float* v0d1      = (const float*)d_in[14];
    const float* v1d1      = (const float*)d_in[15];
    const float* Wd2       = (const float*)d_in[16];
    const float* bd2       = (const float*)d_in[17];
    const float* Wa        = (const float*)d_in[18];
    const float* ba        = (const float*)d_in[19];
    const float* Wb        = (const float*)d_in[20];
    const float* bb        = (const float*)d_in[21];
    const float* gamma     = (const float*)d_in[22];
    const float* logtheta  = (const float*)d_in[23];
    const float* emb_table = (const float*)d_in[24];
    float* out = (float*)d_out;

    char* w = (char*)d_ws;
    auto alloc = [&](size_t bytes) { void* p = (void*)w; w += (bytes + 255) & ~(size_t)255; return p; };
    int*   col_idx = (int*)  alloc((size_t)N * CAP * 4);
    int*   row_cnt = (int*)  alloc((size_t)N * 4);
    unsigned short* Hlin_bf = (unsigned short*)alloc((size_t)N * H1 * 2);
    unsigned short* Hgat_bf = (unsigned short*)alloc((size_t)N * H1 * 2);
    float* Z       = (float*)alloc((size_t)N * H2 * 4);
    unsigned short* Xd_bf   = (unsigned short*)alloc((size_t)N * KD_PAD * 2);
    unsigned short* beta_bf = (unsigned short*)alloc((size_t)N * KB_PAD * 2);
    float* muf     = (float*)alloc((size_t)N * 4);
    float* kco     = (float*)alloc((size_t)N * 4);
    float* hv0     = (float*)alloc((size_t)N * HEADS * 4);
    float* hv1     = (float*)alloc((size_t)N * HEADS * 4);
    float* th_a    = (float*)alloc((size_t)S * G * 4);
    float* eg_a    = (float*)alloc((size_t)S * G * 4);
    float* gm_a    = (float*)alloc((size_t)S * G * 4);
    float* ax_a    = (float*)alloc((size_t)S * G * 4);
    float* Cp      = (float*)alloc((size_t)4 * N * H1 * 4);        // 32 MB split-K partials
    unsigned short* BDb = (unsigned short*)alloc((size_t)N * G * 2);  // 16 MB beta@basis (bf16)
    float* ll_row  = (float*)alloc((size_t)N * 4);
    float* sq_part = (float*)alloc((size_t)N * 16 * 4);
    float* part_ll = (float*)alloc(64 * 4);
    float* part_sq = (float*)alloc(64 * 4);
    unsigned short* nf_bf    = (unsigned short*)alloc((size_t)N * G * 2);
    unsigned short* We1_bf   = (unsigned short*)alloc((size_t)H1 * G * 2);
    unsigned short* W2_bf    = (unsigned short*)alloc((size_t)H2 * H1 * 2);
    unsigned short* Wd1_bf   = (unsigned short*)alloc((size_t)H1 * KD_PAD * 2);
    unsigned short* Wd2_bf   = (unsigned short*)alloc((size_t)G * H1 * 2);
    unsigned short* basisT_bf= (unsigned short*)alloc((size_t)G * KB_PAD * 2);

    // 0. CSR + consolidated prep (tables + all conversions)
    build_csr<<<dim3(N), dim3(64), 0, stream>>>(adj, col_idx, row_cnt);
    prep<<<dim3(PREP_TOTAL / 256), dim3(256), 0, stream>>>(
        logtheta, gamma, th_a, eg_a, gm_a, ax_a,
        node_f, nf_bf, We1, We1_bf, W2, W2_bf, Wd1, Wd1_bf, Wd2, Wd2_bf, basis, basisT_bf);

    // 1. encoder linear, split-K=4 -> reduce -> bf16 Hlin
    gemm_mfma<2, 0, 4><<<dim3(H1 / 128, N / 64, 4), dim3(256), 0, stream>>>(
        nf_bf, We1_bf, be1, Cp, N, H1, G);
    reduce_k<4, 1><<<dim3((N * H1 / 4 + 255) / 256), dim3(256), 0, stream>>>(
        Cp, be1, Hlin_bf, N * H1 / 4, H1 - 1);
    // 2-3. encoder attention
    head_dots<<<dim3(N), dim3(64), 0, stream>>>(Hlin_bf, v0e1, v1e1, hv0, hv1);
    attn_fused<<<dim3(N), dim3(512), 0, stream>>>(Hlin_bf, hv0, hv1, col_idx, row_cnt, Hgat_bf);
    // 4. Z, split-K=8 -> reduce -> fp32 Z
    gemm_mfma<2, 0, 8><<<dim3(H2 / 128, N / 64, 8), dim3(256), 0, stream>>>(
        Hgat_bf, W2_bf, b2, Cp, N, H2, H1);
    reduce_k<8, 0><<<dim3((N * H2 / 4 + 255) / 256), dim3(256), 0, stream>>>(
        Cp, b2, Z, N * H2 / 4, H2 - 1);
    // 5. per-node
    pernode<<<dim3(N), dim3(64), 0, stream>>>(Z, emb_table, slab, Wb, bb, Wa, ba, lib,
                                              beta_bf, muf, kco, Xd_bf);
    // 5b. BD = beta @ basis (MFMA, K=32) -> bf16
    gemm_mfma<2, 1, 1><<<dim3(G / 128, N / 64), dim3(256), 0, stream>>>(
        beta_bf, basisT_bf, nullptr, BDb, N, G, KB_PAD);
    // 5c. NB log-likelihood elementwise
    nb_loss_ew<<<dim3(N / 4), dim3(256), 0, stream>>>(
        BDb, count_m, slab, muf, kco, th_a, eg_a, gm_a, ax_a, ll_row);
    // 6. decoder linear -> bf16
    gemm_mfma<2, 1, 1><<<dim3(H1 / 128, N / 64), dim3(256), 0, stream>>>(
        Xd_bf, Wd1_bf, bd1, Hlin_bf, N, H1, KD_PAD);
    // 7-8. decoder attention
    head_dots<<<dim3(N), dim3(64), 0, stream>>>(Hlin_bf, v0d1, v1d1, hv0, hv1);
    attn_fused<<<dim3(N), dim3(512), 0, stream>>>(Hlin_bf, hv0, hv1, col_idx, row_cnt, Hgat_bf);
    // 9. fused reconstruction GEMM (64x128 tiles) + sq-norm
    gemm_recon_sq<<<dim3(G / 128, N / 64), dim3(256), 0, stream>>>(
        Hgat_bf, Wd2_bf, bd2, nf_bf, sq_part);
    // 10-11. reduce
    row_reduce<<<dim3(64), dim3(64), 0, stream>>>(ll_row, sq_part, part_ll, part_sq);
    finalize2<<<dim3(1), dim3(64), 0, stream>>>(part_ll, part_sq, out);
}

// Round 11
// 186.128 us; speedup vs baseline: 1.3574x; 1.0837x over previous
//
#include <hip/hip_runtime.h>
#include <hip/hip_bf16.h>
#include <math.h>

#define N 4096
#define G 2048
#define H1 512
#define H2 128
#define HEADS 8
#define EMB 16
#define C 20
#define S 4
#define CH 64
#define CIN_D (H2 + EMB)   // 144
#define KD_PAD 160         // CIN_D padded to multiple of 32
#define KB_PAD 32          // C padded to 32
#define CAP 128
#define EPSV 1e-6f

typedef __attribute__((ext_vector_type(8))) short short8;
typedef __attribute__((ext_vector_type(8))) short bf16x8;
typedef __attribute__((ext_vector_type(4))) float f32x4;

__device__ __forceinline__ unsigned short f2b(float x) {
    __hip_bfloat16 h = __float2bfloat16(x);
    return *reinterpret_cast<unsigned short*>(&h);
}
__device__ __forceinline__ float b2f(unsigned short u) {
    unsigned int x = ((unsigned int)u) << 16;
    return __uint_as_float(x);
}
// Stirling lgamma: ~1e-7 rel for x>=8 (shift loop for smaller x; untaken here
// since th = exp(5) ~ 148).
__device__ __forceinline__ float lgamma_fast(float x) {
    float sh = 0.f;
    while (x < 8.f) { sh -= __logf(x); x += 1.f; }
    float ix = 1.f / x;
    float lx = __logf(x);
    return (x - 0.5f) * lx - x + 0.91893853f
         + ix * (0.08333333f - 0.00277778f * ix * ix) + sh;
}

// ---------------- CSR build from dense binary adjacency ----------------
__global__ void build_csr(const float* __restrict__ adj, int* __restrict__ col_idx,
                          int* __restrict__ row_cnt) {
    int i = blockIdx.x;
    int lane = threadIdx.x;  // 64
    int cnt = 0;
    const float4* row4 = (const float4*)(adj + (size_t)i * N);
    int* cols = col_idx + (size_t)i * CAP;
    unsigned long long lmask = (1ull << lane) - 1ull;
    for (int c = 0; c < N / 256; ++c) {
        float4 v = row4[c * 64 + lane];
        float vv[4] = {v.x, v.y, v.z, v.w};
        #pragma unroll
        for (int s = 0; s < 4; ++s) {
            unsigned long long m = __ballot(vv[s] != 0.f);
            if (vv[s] != 0.f) {
                int idx = cnt + __popcll(m & lmask);
                if (idx < CAP) cols[idx] = c * 256 + lane * 4 + s;
            }
            cnt += __popcll(m);
        }
    }
    if (lane == 0) row_cnt[i] = cnt < CAP ? cnt : CAP;
}

// ---------------- consolidated prep: theta tables + all bf16 conversions ----------------
#define SEG_SG   (S * G)                 // 8192
#define SEG_NF4  (N * G / 4)             // 2097152
#define SEG_WE4  (H1 * G / 4)            // 262144
#define SEG_W24  (H2 * H1 / 4)           // 16384
#define SEG_WD1E (H1 * KD_PAD)           // 81920
#define SEG_WD24 (G * H1 / 4)            // 262144
#define SEG_BTE  (G * KB_PAD)            // 65536
#define PREP_TOTAL (SEG_SG + SEG_NF4 + SEG_WE4 + SEG_W24 + SEG_WD1E + SEG_WD24 + SEG_BTE)

__device__ __forceinline__ void cvt4(const float* __restrict__ in,
                                     unsigned short* __restrict__ out, int i) {
    float4 v = ((const float4*)in)[i];
    ushort4 o;
    o.x = f2b(v.x); o.y = f2b(v.y); o.z = f2b(v.z); o.w = f2b(v.w);
    ((ushort4*)out)[i] = o;
}

__global__ __launch_bounds__(256) void prep(const float* __restrict__ logtheta,
                                            const float* __restrict__ gamma,
                                            float* __restrict__ th_a, float* __restrict__ eg_a,
                                            float* __restrict__ gm_a, float* __restrict__ ax_a,
                                            const float* __restrict__ node_f,
                                            unsigned short* __restrict__ nf_bf,
                                            const float* __restrict__ We1,
                                            unsigned short* __restrict__ We1_bf,
                                            const float* __restrict__ W2,
                                            unsigned short* __restrict__ W2_bf,
                                            const float* __restrict__ Wd1,
                                            unsigned short* __restrict__ Wd1_bf,
                                            const float* __restrict__ Wd2,
                                            unsigned short* __restrict__ Wd2_bf,
                                            const float* __restrict__ basis,
                                            unsigned short* __restrict__ basisT_bf) {
    int idx = blockIdx.x * 256 + threadIdx.x;
    if (idx < SEG_SG) {
        float th = __expf(logtheta[idx]);
        float gm = gamma[idx];
        th_a[idx] = th;
        eg_a[idx] = __expf(gm);
        gm_a[idx] = gm;
        ax_a[idx] = th * __logf(th + EPSV) - lgammaf(th + EPSV);
        return;
    }
    idx -= SEG_SG;
    if (idx < SEG_NF4) { cvt4(node_f, nf_bf, idx); return; }
    idx -= SEG_NF4;
    if (idx < SEG_WE4) { cvt4(We1, We1_bf, idx); return; }
    idx -= SEG_WE4;
    if (idx < SEG_W24) { cvt4(W2, W2_bf, idx); return; }
    idx -= SEG_W24;
    if (idx < SEG_WD1E) {
        int n = idx / KD_PAD, k = idx - n * KD_PAD;
        Wd1_bf[idx] = f2b(k < CIN_D ? Wd1[n * CIN_D + k] : 0.f);
        return;
    }
    idx -= SEG_WD1E;
    if (idx < SEG_WD24) { cvt4(Wd2, Wd2_bf, idx); return; }
    idx -= SEG_WD24;
    if (idx < SEG_BTE) {
        int g = idx >> 5, c = idx & 31;
        basisT_bf[idx] = f2b(c < C ? basis[c * G + g] : 0.f);
    }
}

// ---------------- bf16 MFMA GEMM, optional split-K, optional hv epilogue ----------------
#define LDP 40
template<int FM, int OBF, int KS, int HV>
__global__ __launch_bounds__(256) void gemm_mfma(const unsigned short* __restrict__ A,
                                                 const unsigned short* __restrict__ B,
                                                 const float* __restrict__ bias,
                                                 void* __restrict__ Cout,
                                                 int M, int Nc, int K,
                                                 const float* __restrict__ v0f,
                                                 const float* __restrict__ v1f,
                                                 float* __restrict__ hv0,
                                                 float* __restrict__ hv1) {
    constexpr int BMT = FM * 32;
    __shared__ short As[BMT * LDP];
    __shared__ short Bs[128 * LDP];
    int bn = blockIdx.x, bm = blockIdx.y;
    int kz = (KS > 1) ? blockIdx.z : 0;
    int t = threadIdx.x;
    int lane = t & 63, wid = t >> 6;
    int wr = wid >> 1, wc = wid & 1;
    f32x4 acc[FM][4] = {};
    const short* Ag = (const short*)A + (size_t)(bm * BMT) * K;
    const short* Bg = (const short*)B + (size_t)(bn * 128) * K;
    int r0 = t >> 2, q0 = t & 3;
    int rbase = (lane & 15);
    int koff = (lane >> 4) * 8;
    int kbeg = kz * (K / KS), kend = kbeg + K / KS;

    for (int k0 = kbeg; k0 < kend; k0 += 32) {
        short8 a0 = *(const short8*)(Ag + (size_t)r0 * K + k0 + q0 * 8);
        short8 a1;
        if constexpr (FM == 4) a1 = *(const short8*)(Ag + (size_t)(r0 + 64) * K + k0 + q0 * 8);
        short8 b0 = *(const short8*)(Bg + (size_t)r0 * K + k0 + q0 * 8);
        short8 b1 = *(const short8*)(Bg + (size_t)(r0 + 64) * K + k0 + q0 * 8);
        __syncthreads();
        *(short8*)(As + r0 * LDP + q0 * 8) = a0;
        if constexpr (FM == 4) *(short8*)(As + (r0 + 64) * LDP + q0 * 8) = a1;
        *(short8*)(Bs + r0 * LDP + q0 * 8) = b0;
        *(short8*)(Bs + (r0 + 64) * LDP + q0 * 8) = b1;
        __syncthreads();
        bf16x8 af[FM], bfr[4];
        #pragma unroll
        for (int m = 0; m < FM; ++m)
            af[m] = *(const bf16x8*)(As + (wr * FM * 16 + m * 16 + rbase) * LDP + koff);
        #pragma unroll
        for (int n = 0; n < 4; ++n)
            bfr[n] = *(const bf16x8*)(Bs + (wc * 64 + n * 16 + rbase) * LDP + koff);
        #pragma unroll
        for (int m = 0; m < FM; ++m)
            #pragma unroll
            for (int n = 0; n < 4; ++n)
                acc[m][n] = __builtin_amdgcn_mfma_f32_16x16x32_bf16(af[m], bfr[n], acc[m][n], 0, 0, 0);
    }
    int colb = bn * 128 + wc * 64;
    int rowb = bm * BMT + wr * FM * 16;
    #pragma unroll
    for (int m = 0; m < FM; ++m) {
        #pragma unroll
        for (int n = 0; n < 4; ++n) {
            int col = colb + n * 16 + (lane & 15);
            int row0 = rowb + m * 16 + (lane >> 4) * 4;
            if constexpr (KS > 1) {
                float* Cp = (float*)Cout + (size_t)kz * M * Nc;
                #pragma unroll
                for (int r = 0; r < 4; ++r)
                    Cp[(size_t)(row0 + r) * Nc + col] = acc[m][n][r];
            } else {
                float bs = bias ? bias[col] : 0.f;
                #pragma unroll
                for (int r = 0; r < 4; ++r) {
                    float v = acc[m][n][r] + bs;
                    if constexpr (OBF)
                        ((unsigned short*)Cout)[(size_t)(row0 + r) * Nc + col] = f2b(v);
                    else
                        ((float*)Cout)[(size_t)(row0 + r) * Nc + col] = v;
                }
            }
        }
    }
    if constexpr (HV) {
        // wave's 64 cols = one head (CH=64); hv = (Hlin incl. bias) . v per head
        int h = colb >> 6;
        #pragma unroll
        for (int m = 0; m < FM; ++m) {
            #pragma unroll
            for (int r = 0; r < 4; ++r) {
                int row = rowb + m * 16 + (lane >> 4) * 4 + r;
                float p0 = 0.f, p1 = 0.f;
                #pragma unroll
                for (int n = 0; n < 4; ++n) {
                    int col = colb + n * 16 + (lane & 15);
                    float v = acc[m][n][r] + bias[col];
                    p0 += v * v0f[col];
                    p1 += v * v1f[col];
                }
                p0 += __shfl_xor(p0, 1); p0 += __shfl_xor(p0, 2);
                p0 += __shfl_xor(p0, 4); p0 += __shfl_xor(p0, 8);
                p1 += __shfl_xor(p1, 1); p1 += __shfl_xor(p1, 2);
                p1 += __shfl_xor(p1, 4); p1 += __shfl_xor(p1, 8);
                if ((lane & 15) == 0) {
                    hv0[row * HEADS + h] = p0;
                    hv1[row * HEADS + h] = p1;
                }
            }
        }
    }
}

// ---------------- split-K reduce (plain, fp32 out) ----------------
template<int KS>
__global__ __launch_bounds__(256) void reduce_k(const float* __restrict__ Cp,
                                                const float* __restrict__ bias,
                                                float* __restrict__ out,
                                                int total4, int ncmask) {
    int i = blockIdx.x * 256 + threadIdx.x;
    if (i >= total4) return;
    float4 s = ((const float4*)Cp)[i];
    #pragma unroll
    for (int ks = 1; ks < KS; ++ks) {
        float4 v = ((const float4*)(Cp + (size_t)ks * total4 * 4))[i];
        s.x += v.x; s.y += v.y; s.z += v.z; s.w += v.w;
    }
    int col = (i * 4) & ncmask;
    s.x += bias[col]; s.y += bias[col + 1]; s.z += bias[col + 2]; s.w += bias[col + 3];
    ((float4*)out)[i] = s;
}

// ---------------- split-K reduce + bf16 out + fused head dots (Nc=512) ----------------
template<int KS>
__global__ __launch_bounds__(256) void reduce_k_hv(const float* __restrict__ Cp,
                                                   const float* __restrict__ bias,
                                                   unsigned short* __restrict__ out,
                                                   const float* __restrict__ v0f,
                                                   const float* __restrict__ v1f,
                                                   float* __restrict__ hv0,
                                                   float* __restrict__ hv1) {
    constexpr int total4 = N * H1 / 4;
    int t = threadIdx.x;
    int i = blockIdx.x * 256 + t;
    float4 s = ((const float4*)Cp)[i];
    #pragma unroll
    for (int ks = 1; ks < KS; ++ks) {
        float4 v = ((const float4*)(Cp + (size_t)ks * total4 * 4))[i];
        s.x += v.x; s.y += v.y; s.z += v.z; s.w += v.w;
    }
    int col = (i * 4) & (H1 - 1);
    s.x += bias[col]; s.y += bias[col + 1]; s.z += bias[col + 2]; s.w += bias[col + 3];
    ushort4 o;
    o.x = f2b(s.x); o.y = f2b(s.y); o.z = f2b(s.z); o.w = f2b(s.w);
    ((ushort4*)out)[i] = o;
    // head dots: 16 consecutive threads cover one head's 64 channels
    int row = (i * 4) >> 9;
    int h = col >> 6;
    float4 w0 = *(const float4*)(v0f + col);
    float4 w1 = *(const float4*)(v1f + col);
    float p0 = s.x * w0.x + s.y * w0.y + s.z * w0.z + s.w * w0.w;
    float p1 = s.x * w1.x + s.y * w1.y + s.z * w1.z + s.w * w1.w;
    p0 += __shfl_xor(p0, 1); p0 += __shfl_xor(p0, 2);
    p0 += __shfl_xor(p0, 4); p0 += __shfl_xor(p0, 8);
    p1 += __shfl_xor(p1, 1); p1 += __shfl_xor(p1, 2);
    p1 += __shfl_xor(p1, 4); p1 += __shfl_xor(p1, 8);
    if ((t & 15) == 0) {
        hv0[row * HEADS + h] = p0;
        hv1[row * HEADS + h] = p1;
    }
}

// ---------------- fused reconstruction GEMM (64x128 tile) + (nf - Xr)^2 ----------------
__global__ __launch_bounds__(256) void gemm_recon_sq(const unsigned short* __restrict__ A,
                                                     const unsigned short* __restrict__ B,
                                                     const float* __restrict__ bias,
                                                     const unsigned short* __restrict__ nfb,
                                                     float* __restrict__ sq_part) {
    constexpr int K = H1;
    __shared__ short As[64 * LDP];
    __shared__ short Bs[128 * LDP];
    __shared__ float red[4][32];
    int bn = blockIdx.x, bm = blockIdx.y;
    int t = threadIdx.x;
    int lane = t & 63, wid = t >> 6;
    int wr = wid >> 1, wc = wid & 1;
    f32x4 acc[2][4] = {};
    const short* Ag = (const short*)A + (size_t)(bm * 64) * K;
    const short* Bg = (const short*)B + (size_t)(bn * 128) * K;
    int r0 = t >> 2, q0 = t & 3;
    int rbase = (lane & 15);
    int koff = (lane >> 4) * 8;

    for (int k0 = 0; k0 < K; k0 += 32) {
        short8 a0 = *(const short8*)(Ag + (size_t)r0 * K + k0 + q0 * 8);
        short8 b0 = *(const short8*)(Bg + (size_t)r0 * K + k0 + q0 * 8);
        short8 b1 = *(const short8*)(Bg + (size_t)(r0 + 64) * K + k0 + q0 * 8);
        __syncthreads();
        *(short8*)(As + r0 * LDP + q0 * 8) = a0;
        *(short8*)(Bs + r0 * LDP + q0 * 8) = b0;
        *(short8*)(Bs + (r0 + 64) * LDP + q0 * 8) = b1;
        __syncthreads();
        bf16x8 af[2], bfr[4];
        #pragma unroll
        for (int m = 0; m < 2; ++m)
            af[m] = *(const bf16x8*)(As + (wr * 32 + m * 16 + rbase) * LDP + koff);
        #pragma unroll
        for (int n = 0; n < 4; ++n)
            bfr[n] = *(const bf16x8*)(Bs + (wc * 64 + n * 16 + rbase) * LDP + koff);
        #pragma unroll
        for (int m = 0; m < 2; ++m)
            #pragma unroll
            for (int n = 0; n < 4; ++n)
                acc[m][n] = __builtin_amdgcn_mfma_f32_16x16x32_bf16(af[m], bfr[n], acc[m][n], 0, 0, 0);
    }
    int colb = bn * 128 + wc * 64;
    int rowb = bm * 64 + wr * 32;
    float part[2][4];
    #pragma unroll
    for (int m = 0; m < 2; ++m) {
        #pragma unroll
        for (int r = 0; r < 4; ++r) part[m][r] = 0.f;
        #pragma unroll
        for (int n = 0; n < 4; ++n) {
            int col = colb + n * 16 + (lane & 15);
            float bs = bias[col];
            int row0 = rowb + m * 16 + (lane >> 4) * 4;
            #pragma unroll
            for (int r = 0; r < 4; ++r) {
                float d = b2f(nfb[(size_t)(row0 + r) * G + col]) - (acc[m][n][r] + bs);
                part[m][r] += d * d;
            }
        }
    }
    #pragma unroll
    for (int m = 0; m < 2; ++m)
        #pragma unroll
        for (int r = 0; r < 4; ++r) {
            float v = part[m][r];
            v += __shfl_xor(v, 1); v += __shfl_xor(v, 2);
            v += __shfl_xor(v, 4); v += __shfl_xor(v, 8);
            part[m][r] = v;
        }
    if ((lane & 15) == 0) {
        int q = lane >> 4;
        #pragma unroll
        for (int m = 0; m < 2; ++m)
            #pragma unroll
            for (int r = 0; r < 4; ++r)
                red[wid][m * 16 + q * 4 + r] = part[m][r];
    }
    __syncthreads();
    if (t < 64) {
        int wr2 = t >> 5, loc = t & 31;
        float v = red[wr2 * 2 + 0][loc] + red[wr2 * 2 + 1][loc];
        sq_part[(size_t)(bm * 64 + t) * 16 + bn] = v;
    }
}

// ---------------- fused beta@basis GEMM + NB log-likelihood (32x128 tile) ----------------
// grid (G/128=16, N/32=128) = 2048 blocks; acc only 16 VGPR; SoA tables, Stirling.
__global__ __launch_bounds__(256) void bd_ll(const unsigned short* __restrict__ A,  // beta_bf [N][32]
                                             const unsigned short* __restrict__ B,  // basisT [G][32]
                                             const float* __restrict__ cm,
                                             const int* __restrict__ slab,
                                             const float* __restrict__ muf,
                                             const float* __restrict__ kco,
                                             const float* __restrict__ th_a,
                                             const float* __restrict__ eg_a,
                                             const float* __restrict__ gm_a,
                                             const float* __restrict__ ax_a,
                                             float* __restrict__ ll_part) {
    __shared__ short As[32 * LDP];
    __shared__ short Bs[128 * LDP];
    __shared__ float red[4][16];
    int bn = blockIdx.x, bm = blockIdx.y;
    int t = threadIdx.x;
    int lane = t & 63, wid = t >> 6;
    int wr = wid >> 1, wc = wid & 1;
    f32x4 acc[4] = {};
    const short* Ag = (const short*)A + (size_t)(bm * 32) * KB_PAD;
    const short* Bg = (const short*)B + (size_t)(bn * 128) * KB_PAD;
    int r0 = t >> 2, q0 = t & 3;
    if (t < 128) {
        short8 a0 = *(const short8*)(Ag + (size_t)r0 * KB_PAD + q0 * 8);
        *(short8*)(As + r0 * LDP + q0 * 8) = a0;
    }
    {
        short8 b0 = *(const short8*)(Bg + (size_t)r0 * KB_PAD + q0 * 8);
        short8 b1 = *(const short8*)(Bg + (size_t)(r0 + 64) * KB_PAD + q0 * 8);
        *(short8*)(Bs + r0 * LDP + q0 * 8) = b0;
        *(short8*)(Bs + (r0 + 64) * LDP + q0 * 8) = b1;
    }
    __syncthreads();
    int rbase = (lane & 15);
    int koff = (lane >> 4) * 8;
    bf16x8 af = *(const bf16x8*)(As + (wr * 16 + rbase) * LDP + koff);
    bf16x8 bfr[4];
    #pragma unroll
    for (int n = 0; n < 4; ++n)
        bfr[n] = *(const bf16x8*)(Bs + (wc * 64 + n * 16 + rbase) * LDP + koff);
    #pragma unroll
    for (int n = 0; n < 4; ++n)
        acc[n] = __builtin_amdgcn_mfma_f32_16x16x32_bf16(af, bfr[n], acc[n], 0, 0, 0);
    // epilogue: NB log-likelihood on 16 elems/lane, row-reduce
    int colb = bn * 128 + wc * 64;
    int rowb = bm * 32 + wr * 16;
    #pragma unroll
    for (int r = 0; r < 4; ++r) {
        int row = rowb + (lane >> 4) * 4 + r;
        int sl = slab[row];
        float mufv = muf[row], kcov = kco[row];
        size_t sgb = (size_t)sl * G;
        float p = 0.f;
        #pragma unroll
        for (int n = 0; n < 4; ++n) {
            int col = colb + n * 16 + (lane & 15);
            float ebd = acc[n][r] + EPSV;   // bd >= 0
            float k = cm[(size_t)row * G + col];
            float th = th_a[sgb + col];
            float lbd = __logf(ebd);
            float mu = mufv * ebd * eg_a[sgb + col];
            float lgx = lgamma_fast(k + th + EPSV);
            p += lgx + ax_a[sgb + col] - (th + k) * __logf(th + mu + EPSV)
               + k * (kcov + lbd + gm_a[sgb + col]);
        }
        p += __shfl_xor(p, 1); p += __shfl_xor(p, 2);
        p += __shfl_xor(p, 4); p += __shfl_xor(p, 8);
        if ((lane & 15) == 0) red[wid][(lane >> 4) * 4 + r] = p;
    }
    __syncthreads();
    if (t < 32) {
        int wr2 = t >> 4, rl = t & 15;
        float v = red[wr2 * 2 + 0][rl] + red[wr2 * 2 + 1][rl];
        ll_part[(size_t)(bm * 32 + wr2 * 16 + rl) * 16 + bn] = v;
    }
}

// ---------------- fused attention: weights in LDS + aggregation + elu -> bf16 ----------------
__global__ __launch_bounds__(512) void attn_fused(const unsigned short* __restrict__ Hb,
                                                  const float* __restrict__ hv0,
                                                  const float* __restrict__ hv1,
                                                  const int* __restrict__ col_idx,
                                                  const int* __restrict__ row_cnt,
                                                  unsigned short* __restrict__ out) {
    __shared__ int scols[CAP];
    __shared__ float sw[CAP][HEADS];     // 4 KB
    __shared__ float sden[HEADS];
    __shared__ float red[8][64 * 8];     // 16 KB
    int i = blockIdx.x;
    int t = threadIdx.x;
    int cnt = row_cnt[i];
    const int* cols = col_idx + (size_t)i * CAP;
    if (t < cnt) scols[t] = cols[t];
    __syncthreads();
    for (int idx = t; idx < cnt * HEADS; idx += 512) {
        int e = idx >> 3, h = idx & 7;
        int j = scols[e];
        float x = hv0[i * HEADS + h] + hv1[j * HEADS + h];
        sw[e][h] = __expf(1.f / (1.f + __expf(-x)) - 0.5f);
    }
    __syncthreads();
    if (t < HEADS) {
        float d = 0.f;
        for (int e = 0; e < cnt; ++e) d += sw[e][t];
        sden[t] = 1.f / d;     // den > 0 (self-loop)
    }
    __syncthreads();
    int slot = t >> 6;
    int cg = t & 63;
    int h = cg >> 3;
    float inv = sden[h];
    float acc[8];
    #pragma unroll
    for (int k = 0; k < 8; ++k) acc[k] = 0.f;
    for (int e = slot; e < cnt; e += 8) {
        int j = scols[e];
        float wv = sw[e][h] * inv;
        short8 hv = ((const short8*)(Hb + (size_t)j * H1))[cg];
        #pragma unroll
        for (int k = 0; k < 8; ++k)
            acc[k] += wv * b2f((unsigned short)hv[k]);
    }
    #pragma unroll
    for (int k = 0; k < 8; ++k) red[slot][cg * 8 + k] = acc[k];
    __syncthreads();
    if (slot < 4) {
        #pragma unroll
        for (int k = 0; k < 8; ++k) red[slot][cg * 8 + k] += red[slot + 4][cg * 8 + k];
    }
    __syncthreads();
    if (slot < 2) {
        #pragma unroll
        for (int k = 0; k < 8; ++k) red[slot][cg * 8 + k] += red[slot + 2][cg * 8 + k];
    }
    __syncthreads();
    if (slot == 0) {
        short8 o;
        #pragma unroll
        for (int k = 0; k < 8; ++k) {
            float v = red[0][cg * 8 + k] + red[1][cg * 8 + k];
            v = (v > 0.f) ? v : expm1f(v);
            o[k] = (short)f2b(v);
        }
        ((short8*)(out + (size_t)i * H1))[cg] = o;
    }
}

// ---------------- per-node: beta_bf (padded), muf/kco, Xd_bf ----------------
__global__ void pernode(const float* __restrict__ Z, const float* __restrict__ emb_table,
                        const int* __restrict__ slab, const float* __restrict__ Wb,
                        const float* __restrict__ bb, const float* __restrict__ Wa,
                        const float* __restrict__ ba, const float* __restrict__ lib,
                        unsigned short* __restrict__ beta_bf, float* __restrict__ muf,
                        float* __restrict__ kco, unsigned short* __restrict__ Xdb) {
    int i = blockIdx.x;
    int lane = threadIdx.x;  // 64
    __shared__ float sZ[H2];
    __shared__ float sE[EMB];
    __shared__ float sLog[C];
    __shared__ float sAl;
    sZ[lane] = Z[(size_t)i * H2 + lane];
    sZ[64 + lane] = Z[(size_t)i * H2 + 64 + lane];
    int s = slab[i];
    if (lane < EMB) sE[lane] = emb_table[s * EMB + lane];
    __syncthreads();
    Xdb[(size_t)i * KD_PAD + lane] = f2b(sZ[lane]);
    Xdb[(size_t)i * KD_PAD + 64 + lane] = f2b(sZ[64 + lane]);
    if (lane < EMB) Xdb[(size_t)i * KD_PAD + H2 + lane] = f2b(sE[lane]);
    if (lane < KD_PAD - CIN_D) Xdb[(size_t)i * KD_PAD + CIN_D + lane] = 0;
    if (lane < C) {
        float acc = bb[lane];
        for (int k = 0; k < H2; ++k) {
            float z = sZ[k];
            float e = z > 0.f ? z : expm1f(z);
            acc += e * Wb[lane * H2 + k];
        }
        sLog[lane] = acc;
    }
    __syncthreads();
    if (lane == 0) {
        float mx = sLog[0];
        for (int c = 1; c < C; ++c) mx = fmaxf(mx, sLog[c]);
        float sm = 0.f;
        for (int c = 0; c < C; ++c) { float e = __expf(sLog[c] - mx); sLog[c] = e; sm += e; }
        for (int c = 0; c < C; ++c) sLog[c] /= sm;
    }
    __syncthreads();
    if (lane < KB_PAD) beta_bf[(size_t)i * KB_PAD + lane] = (lane < C) ? f2b(sLog[lane]) : 0;
    float x0 = sZ[lane];        x0 = x0 > 0.f ? x0 : expm1f(x0);
    float x1 = sZ[64 + lane];   x1 = x1 > 0.f ? x1 : expm1f(x1);
    float p = x0 * Wa[lane] + x1 * Wa[64 + lane];
    if (lane < EMB) {
        float x2 = sE[lane];    x2 = x2 > 0.f ? x2 : expm1f(x2);
        p += x2 * Wa[H2 + lane];
    }
    #pragma unroll
    for (int m = 32; m; m >>= 1) p += __shfl_xor(p, m);
    if (lane == 0) sAl = p + ba[0];
    __syncthreads();
    if (lane == 0) {
        float A = sAl, L = lib[i];
        muf[i] = L * __expf(A);
        kco[i] = __logf(L) + A;
    }
}

// ---------------- two-stage final reduce ----------------
__global__ void row_reduce(const float* __restrict__ ll_part, const float* __restrict__ sq_part,
                           float* __restrict__ part_ll, float* __restrict__ part_sq) {
    int blk = blockIdx.x, lane = threadIdx.x;
    int row = blk * 64 + lane;
    float s1 = 0.f, s2 = 0.f;
    #pragma unroll
    for (int j = 0; j < 16; ++j) {
        s1 += ll_part[(size_t)row * 16 + j];
        s2 += sq_part[(size_t)row * 16 + j];
    }
    float b = sqrtf(s2);
    #pragma unroll
    for (int m = 32; m; m >>= 1) { s1 += __shfl_xor(s1, m); b += __shfl_xor(b, m); }
    if (lane == 0) { part_ll[blk] = s1; part_sq[blk] = b; }
}

__global__ void finalize2(const float* __restrict__ part_ll, const float* __restrict__ part_sq,
                          float* __restrict__ out) {
    int lane = threadIdx.x;
    float a = part_ll[lane], b = part_sq[lane];
    #pragma unroll
    for (int m = 32; m; m >>= 1) { a += __shfl_xor(a, m); b += __shfl_xor(b, m); }
    if (lane == 0) out[0] = -(a / (float)N) + 0.1f * (b / (float)N);
}

extern "C" void kernel_launch(void* const* d_in, const int* in_sizes, int n_in,
                              void* d_out, int out_size, void* d_ws, size_t ws_size,
                              hipStream_t stream) {
    const float* adj       = (const float*)d_in[0];
    const float* node_f    = (const float*)d_in[1];
    const float* count_m   = (const float*)d_in[2];
    const float* lib       = (const float*)d_in[3];
    const int*   slab      = (const int*)d_in[4];
    const float* basis     = (const float*)d_in[5];
    const float* We1       = (const float*)d_in[6];
    const float* be1       = (const float*)d_in[7];
    const float* v0e1      = (const float*)d_in[8];
    const float* v1e1      = (const float*)d_in[9];
    const float* W2        = (const float*)d_in[10];
    const float* b2        = (const float*)d_in[11];
    const float* Wd1       = (const float*)d_in[12];
    const float* bd1       = (const float*)d_in[13];
    const float* v0d1      = (const float*)d_in[14];
    const float* v1d1      = (const float*)d_in[15];
    const float* Wd2       = (const float*)d_in[16];
    const float* bd2       = (const float*)d_in[17];
    const float* Wa        = (const float*)d_in[18];
    const float* ba        = (const float*)d_in[19];
    const float* Wb        = (const float*)d_in[20];
    const float* bb        = (const float*)d_in[21];
    const float* gamma     = (const float*)d_in[22];
    const float* logtheta  = (const float*)d_in[23];
    const float* emb_table = (const float*)d_in[24];
    float* out = (float*)d_out;

    char* w = (char*)d_ws;
    auto alloc = [&](size_t bytes) { void* p = (void*)w; w += (bytes + 255) & ~(size_t)255; return p; };
    int*   col_idx = (int*)  alloc((size_t)N * CAP * 4);
    int*   row_cnt = (int*)  alloc((size_t)N * 4);
    unsigned short* Hlin_bf = (unsigned short*)alloc((size_t)N * H1 * 2);
    unsigned short* Hgat_bf = (unsigned short*)alloc((size_t)N * H1 * 2);
    float* Z       = (float*)alloc((size_t)N * H2 * 4);
    unsigned short* Xd_bf   = (unsigned short*)alloc((size_t)N * KD_PAD * 2);
    unsigned short* beta_bf = (unsigned short*)alloc((size_t)N * KB_PAD * 2);
    float* muf     = (float*)alloc((size_t)N * 4);
    float* kco     = (float*)alloc((size_t)N * 4);
    float* hv0     = (float*)alloc((size_t)N * HEADS * 4);
    float* hv1     = (float*)alloc((size_t)N * HEADS * 4);
    float* th_a    = (float*)alloc((size_t)S * G * 4);
    float* eg_a    = (float*)alloc((size_t)S * G * 4);
    float* gm_a    = (float*)alloc((size_t)S * G * 4);
    float* ax_a    = (float*)alloc((size_t)S * G * 4);
    float* Cp      = (float*)alloc((size_t)4 * N * H1 * 4);        // 32 MB split-K partials
    float* ll_part = (float*)alloc((size_t)N * 16 * 4);
    float* sq_part = (float*)alloc((size_t)N * 16 * 4);
    float* part_ll = (float*)alloc(64 * 4);
    float* part_sq = (float*)alloc(64 * 4);
    unsigned short* nf_bf    = (unsigned short*)alloc((size_t)N * G * 2);
    unsigned short* We1_bf   = (unsigned short*)alloc((size_t)H1 * G * 2);
    unsigned short* W2_bf    = (unsigned short*)alloc((size_t)H2 * H1 * 2);
    unsigned short* Wd1_bf   = (unsigned short*)alloc((size_t)H1 * KD_PAD * 2);
    unsigned short* Wd2_bf   = (unsigned short*)alloc((size_t)G * H1 * 2);
    unsigned short* basisT_bf= (unsigned short*)alloc((size_t)G * KB_PAD * 2);

    // 0. CSR + consolidated prep
    build_csr<<<dim3(N), dim3(64), 0, stream>>>(adj, col_idx, row_cnt);
    prep<<<dim3(PREP_TOTAL / 256), dim3(256), 0, stream>>>(
        logtheta, gamma, th_a, eg_a, gm_a, ax_a,
        node_f, nf_bf, We1, We1_bf, W2, W2_bf, Wd1, Wd1_bf, Wd2, Wd2_bf, basis, basisT_bf);

    // 1. encoder linear, split-K=4 -> reduce(+head dots) -> bf16 Hlin + hv
    gemm_mfma<2, 0, 4, 0><<<dim3(H1 / 128, N / 64, 4), dim3(256), 0, stream>>>(
        nf_bf, We1_bf, be1, Cp, N, H1, G, nullptr, nullptr, nullptr, nullptr);
    reduce_k_hv<4><<<dim3(N * H1 / 4 / 256), dim3(256), 0, stream>>>(
        Cp, be1, Hlin_bf, v0e1, v1e1, hv0, hv1);
    // 2. encoder attention
    attn_fused<<<dim3(N), dim3(512), 0, stream>>>(Hlin_bf, hv0, hv1, col_idx, row_cnt, Hgat_bf);
    // 3. Z, split-K=8 -> reduce -> fp32 Z
    gemm_mfma<2, 0, 8, 0><<<dim3(H2 / 128, N / 64, 8), dim3(256), 0, stream>>>(
        Hgat_bf, W2_bf, b2, Cp, N, H2, H1, nullptr, nullptr, nullptr, nullptr);
    reduce_k<8><<<dim3((N * H2 / 4 + 255) / 256), dim3(256), 0, stream>>>(
        Cp, b2, Z, N * H2 / 4, H2 - 1);
    // 4. per-node
    pernode<<<dim3(N), dim3(64), 0, stream>>>(Z, emb_table, slab, Wb, bb, Wa, ba, lib,
                                              beta_bf, muf, kco, Xd_bf);
    // 5. fused beta@basis GEMM + NB log-likelihood
    bd_ll<<<dim3(G / 128, N / 32), dim3(256), 0, stream>>>(
        beta_bf, basisT_bf, count_m, slab, muf, kco, th_a, eg_a, gm_a, ax_a, ll_part);
    // 6. decoder linear -> bf16 + head dots in epilogue
    gemm_mfma<2, 1, 1, 1><<<dim3(H1 / 128, N / 64), dim3(256), 0, stream>>>(
        Xd_bf, Wd1_bf, bd1, Hlin_bf, N, H1, KD_PAD, v0d1, v1d1, hv0, hv1);
    // 7. decoder attention
    attn_fused<<<dim3(N), dim3(512), 0, stream>>>(Hlin_bf, hv0, hv1, col_idx, row_cnt, Hgat_bf);
    // 8. fused reconstruction GEMM + sq-norm
    gemm_recon_sq<<<dim3(G / 128, N / 64), dim3(256), 0, stream>>>(
        Hgat_bf, Wd2_bf, bd2, nf_bf, sq_part);
    // 9-10. reduce
    row_reduce<<<dim3(64), dim3(64), 0, stream>>>(ll_part, sq_part, part_ll, part_sq);
    finalize2<<<dim3(1), dim3(64), 0, stream>>>(part_ll, part_sq, out);
}